// Round 8
// baseline (428.854 us; speedup 1.0000x reference)
//
#include <hip/hip_runtime.h>
#include <stdint.h>

typedef unsigned short ushort_t;

#define NNODES 50000
#define NEDGES 800000
#define DD 128
#define EB 128                     // edges per block (fallback MFMA path)

typedef short bf16x8 __attribute__((ext_vector_type(8)));
typedef float f32x16 __attribute__((ext_vector_type(16)));

// ---------------- fallback ws layout (bytes) — rounds 3-5, proven ----------
#define XH_OFF    0u
#define XL_OFF    12800000u
#define W1P_OFF   25600000u
#define W2P_OFF   25731072u
#define WS_MIN    25796608u
#define DEG_OFF   25796608u
#define ELIST_OFF 25996800u
#define CUR_OFF   29196800u
#define WS_CSR    29396992u

// ---------------- factored-path ws layout (bytes) ----------------
#define PQ_OFF2   0u                    // 50000*256*4 = 51,200,000
#define W1P_OFF2  51200000u             // 131072
#define U2P_OFF2  51331072u             // 65536
#define WNP_OFF2  51396608u             // 131072
#define W2U_OFF2  51527680u             // 65536
#define VV_OFF2   51593216u             // 512
#define DEG_OFF2  51593728u             // 200192
#define CUR_OFF2  51793920u             // 200192
#define BSUM_OFF2 51994112u             // 256
#define EL_OFF2   51994368u             // 3,200,000 (elist) or 6,400,000 (epair)
#define WS_NEW    55194368u             // round-7 proven path
#define WS_NEW2   58394368u             // epair path (int2[800000])

#define NB_SCAN 49                      // ceil(50000/1024)

// ---------------------------------------------------------------------------
__global__ void zero_kernel(float4* __restrict__ p, int n4) {
    int i = blockIdx.x * blockDim.x + threadIdx.x;
    if (i < n4) p[i] = make_float4(0.f, 0.f, 0.f, 0.f);
}
__global__ void zero_i32(int* __restrict__ p, int n) {
    int i = blockIdx.x * blockDim.x + threadIdx.x;
    if (i < n) p[i] = 0;
}
// fused: zero out [1.6M float4] + deg [12512 int4]
__global__ void zero_all(float4* __restrict__ out, int4* __restrict__ deg4) {
    int i = blockIdx.x * blockDim.x + threadIdx.x;
    if (i < 1600000) out[i] = make_float4(0.f, 0.f, 0.f, 0.f);
    else if (i < 1600000 + 12512) deg4[i - 1600000] = make_int4(0, 0, 0, 0);
}

__device__ inline void bf16_split(float f, ushort_t& hi, ushort_t& lo) {
    uint32_t b = __float_as_uint(f);
    uint32_t hb = b & 0xFFFF0000u;
    hi = (ushort_t)(b >> 16);
    float lof = f - __uint_as_float(hb);
    lo = (ushort_t)(__float_as_uint(lof) >> 16);
}

__global__ void pack_x(const float* __restrict__ x,
                       ushort_t* __restrict__ xh, ushort_t* __restrict__ xl) {
    int i = blockIdx.x * blockDim.x + threadIdx.x;
    if (i >= NNODES * DD) return;
    ushort_t h, l;
    bf16_split(x[i], h, l);
    xh[i] = h; xl[i] = l;
}

// Pack W [K][128] -> per-ktile fragment order, hi plane then lo plane.
__global__ void pack_w(const float* __restrict__ W, ushort_t* __restrict__ wp,
                       int K) {
    int i = blockIdx.x * blockDim.x + threadIdx.x;
    if (i >= K * 128) return;
    int k = i >> 7, n = i & 127;
    int base = (k >> 4) * 4096 + ((((k >> 3) & 1) * 128 + n) << 3) + (k & 7);
    ushort_t h, l;
    bf16_split(W[i], h, l);
    wp[base] = h; wp[base + 2048] = l;
}

// fused pack of mW1 (K=256) + uW2 (K=128) + uW1-top (K=128) in one launch
__global__ void pack3(const float* __restrict__ mW1, const float* __restrict__ uW2,
                      const float* __restrict__ uW1,
                      ushort_t* __restrict__ w1p, ushort_t* __restrict__ u2p,
                      ushort_t* __restrict__ wnp) {
    int i = blockIdx.x * blockDim.x + threadIdx.x;   // 0..65535
    const float* W; ushort_t* wp; int li;
    if (i < 32768)      { W = mW1; wp = w1p; li = i; }
    else if (i < 49152) { W = uW2; wp = u2p; li = i - 32768; }
    else                { W = uW1; wp = wnp; li = i - 49152; }
    int k = li >> 7, n = li & 127;
    int base = (k >> 4) * 4096 + ((((k >> 3) & 1) * 128 + n) << 3) + (k & 7);
    ushort_t h, l;
    bf16_split(W[li], h, l);
    wp[base] = h; wp[base + 2048] = l;
}

// ---------------- CSR build ----------------
__global__ void hist_kernel(const int* __restrict__ ei, int* __restrict__ deg) {
    int i = blockIdx.x * blockDim.x + threadIdx.x;
    if (i < NEDGES) atomicAdd(&deg[ei[NEDGES + i]], 1);
}

// single-block scan (fallback path only)
__global__ __launch_bounds__(1024)
void scan_kernel(const int* __restrict__ deg, int* __restrict__ cursor) {
    __shared__ int part[1024];
    const int t = threadIdx.x;
    const int CH = 49;
    int s = 0;
#pragma unroll 1
    for (int i = 0; i < CH; ++i) {
        int idx = t * CH + i;
        if (idx < NNODES) s += deg[idx];
    }
    part[t] = s;
    __syncthreads();
    for (int d = 1; d < 1024; d <<= 1) {
        int v = (t >= d) ? part[t - d] : 0;
        __syncthreads();
        part[t] += v;
        __syncthreads();
    }
    int run = (t == 0) ? 0 : part[t - 1];
#pragma unroll 1
    for (int i = 0; i < CH; ++i) {
        int idx = t * CH + i;
        if (idx < NNODES) {
            cursor[idx] = run;
            run += deg[idx];
        }
    }
}

// parallel scan
__global__ __launch_bounds__(1024)
void scanA(const int* __restrict__ deg, int* __restrict__ cur,
           int* __restrict__ bsum) {
    __shared__ int sm[1024];
    const int t = threadIdx.x;
    const int idx = blockIdx.x * 1024 + t;
    int d = (idx < NNODES) ? deg[idx] : 0;
    sm[t] = d;
    __syncthreads();
    for (int off = 1; off < 1024; off <<= 1) {
        int v = 0;
        if (t >= off) v = sm[t - off];
        __syncthreads();
        sm[t] += v;
        __syncthreads();
    }
    if (idx < NNODES) cur[idx] = sm[t];          // inclusive within block
    if (t == 1023) bsum[blockIdx.x] = sm[1023];  // raw block sum
}
__global__ void scanB(int* __restrict__ bsum, int nb) {
    if (threadIdx.x == 0) {
        int run = 0;
        for (int i = 0; i < nb; ++i) { int v = bsum[i]; bsum[i] = run; run += v; }
    }
}
__global__ __launch_bounds__(1024)
void scanC(const int* __restrict__ deg, int* __restrict__ cur,
           const int* __restrict__ bsum) {
    const int idx = blockIdx.x * 1024 + threadIdx.x;
    if (idx < NNODES) cur[idx] = cur[idx] - deg[idx] + bsum[blockIdx.x];
}
// scanC with scanB folded in (bsum holds RAW block sums)
__global__ __launch_bounds__(1024)
void scanC2(const int* __restrict__ deg, int* __restrict__ cur,
            const int* __restrict__ bsum) {
    int pre = 0;
#pragma unroll 1
    for (int j = 0; j < blockIdx.x; ++j) pre += bsum[j];
    const int idx = blockIdx.x * 1024 + threadIdx.x;
    if (idx < NNODES) cur[idx] = cur[idx] - deg[idx] + pre;
}

__global__ void fill_kernel(const int* __restrict__ ei, int* __restrict__ cursor,
                            int* __restrict__ elist) {
    int i = blockIdx.x * blockDim.x + threadIdx.x;
    if (i < NEDGES) {
        int pos = atomicAdd(&cursor[ei[NEDGES + i]], 1);
        elist[pos] = i;
    }
}
// fill packed (src,dst) pairs in dest-sorted order
__global__ void fill2_kernel(const int* __restrict__ ei, int* __restrict__ cursor,
                             int2* __restrict__ ep) {
    int i = blockIdx.x * blockDim.x + threadIdx.x;
    if (i < NEDGES) {
        int c = ei[NEDGES + i];
        int pos = atomicAdd(&cursor[c], 1);
        ep[pos] = make_int2(ei[i], c);
    }
}

// ---------------- small precomputes ----------------
__global__ void w2u_kernel(const float* __restrict__ W2,
                           const float* __restrict__ U1, float* __restrict__ W2U) {
    int id = blockIdx.x * 256 + threadIdx.x;
    if (id >= 128 * 128) return;
    int i = id >> 7, j = id & 127;
    float s = 0.f;
    for (int k = 0; k < 128; ++k) s += W2[i * 128 + k] * U1[(128 + k) * 128 + j];
    W2U[id] = s;
}
__global__ void vvec_kernel(const float* __restrict__ b2,
                            const float* __restrict__ U1, float* __restrict__ vv) {
    int j = threadIdx.x;
    if (j >= 128) return;
    float s = 0.f;
    for (int k = 0; k < 128; ++k) s += b2[k] * U1[(128 + k) * 128 + j];
    vv[j] = s;
}
// fused W2U + vv (grid 65: blocks 0..63 = W2U, block 64 = vv)
__global__ void w2u_vv(const float* __restrict__ W2, const float* __restrict__ b2,
                       const float* __restrict__ U1,
                       float* __restrict__ W2U, float* __restrict__ vv) {
    if (blockIdx.x < 64) {
        int id = blockIdx.x * 256 + threadIdx.x;
        int i = id >> 7, j = id & 127;
        float s = 0.f;
        for (int k = 0; k < 128; ++k)
            s += W2[i * 128 + k] * U1[(128 + k) * 128 + j];
        W2U[id] = s;
    } else if (threadIdx.x < 128) {
        int j = threadIdx.x;
        float s = 0.f;
        for (int k = 0; k < 128; ++k)
            s += b2[k] * U1[(128 + k) * 128 + j];
        vv[j] = s;
    }
}

// ---------------------------------------------------------------------------
// PQ GEMM: PQ[n][0:128] = x[n]@W1t + b1 ; PQ[n][128:256] = x[n]@W1b
__global__ __launch_bounds__(256)
void pq_gemm(const float* __restrict__ x, const ushort_t* __restrict__ w1p,
             const float* __restrict__ b1, float* __restrict__ PQ) {
    __shared__ __align__(16) ushort_t Wst[4096];
    const int t = threadIdx.x, w = t >> 6, l = t & 63;
    const int lh = l >> 5, ln = l & 31;
    const int base = blockIdx.x * 128;
    const int c = blockIdx.y;
    const int row = base + w * 32 + ln;
    const float* ax = x + (size_t)min(row, NNODES - 1) * DD;
    const ushort_t* wt = w1p + c * 8 * 4096;

    f32x16 acc[4];
#pragma unroll
    for (int tt = 0; tt < 4; ++tt)
#pragma unroll
        for (int q = 0; q < 16; ++q) acc[tt][q] = 0.f;

    float4 pfh = *(const float4*)(wt + t * 8);
    float4 pfl = *(const float4*)(wt + 2048 + t * 8);
    for (int u = 0; u < 8; ++u) {
        __syncthreads();
        *(float4*)(Wst + t * 8)        = pfh;
        *(float4*)(Wst + 2048 + t * 8) = pfl;
        float4 a0 = *(const float4*)(ax + u * 16 + lh * 8);
        float4 a1 = *(const float4*)(ax + u * 16 + lh * 8 + 4);
        if (u < 7) {
            pfh = *(const float4*)(wt + (u + 1) * 4096 + t * 8);
            pfl = *(const float4*)(wt + (u + 1) * 4096 + 2048 + t * 8);
        }
        float av[8] = {a0.x, a0.y, a0.z, a0.w, a1.x, a1.y, a1.z, a1.w};
        bf16x8 a_hi, a_lo;
#pragma unroll
        for (int q = 0; q < 8; ++q) {
            ushort_t h, lo16;
            bf16_split(av[q], h, lo16);
            a_hi[q] = (short)h; a_lo[q] = (short)lo16;
        }
        __syncthreads();
#pragma unroll
        for (int tt = 0; tt < 4; ++tt) {
            const int boff = (lh * 128 + tt * 32 + ln) * 8;
            bf16x8 bh = *(const bf16x8*)(Wst + boff);
            bf16x8 bl = *(const bf16x8*)(Wst + 2048 + boff);
            acc[tt] = __builtin_amdgcn_mfma_f32_32x32x16_bf16(a_hi, bh, acc[tt], 0, 0, 0);
            acc[tt] = __builtin_amdgcn_mfma_f32_32x32x16_bf16(a_hi, bl, acc[tt], 0, 0, 0);
            acc[tt] = __builtin_amdgcn_mfma_f32_32x32x16_bf16(a_lo, bh, acc[tt], 0, 0, 0);
        }
    }
    float bias[4];
#pragma unroll
    for (int tt = 0; tt < 4; ++tt)
        bias[tt] = (c == 0) ? b1[tt * 32 + ln] : 0.f;
#pragma unroll
    for (int tt = 0; tt < 4; ++tt) {
#pragma unroll
        for (int r = 0; r < 16; ++r) {
            int mrow = w * 32 + (r & 3) + 8 * (r >> 2) + 4 * lh;
            int n = base + mrow;
            if (n < NNODES)
                PQ[(size_t)n * 256 + c * 128 + tt * 32 + ln] = acc[tt][r] + bias[tt];
        }
    }
}

// ---------------------------------------------------------------------------
// Edge elementwise (round-7 proven, elist indirection, EW_C=4)
#define EW_C 4
__global__ __launch_bounds__(256)
void edge_ew(const float* __restrict__ PQ, const int* __restrict__ ei,
             const int* __restrict__ elist, float* Hsum) {
    const int t = threadIdx.x, w = t >> 6, l = t & 63;
    const int start = blockIdx.x * 512 + w * 128;
    if (start >= NEDGES) return;
    const int end = min(start + 128, NEDGES);

    float sx = 0.f, sy = 0.f;
    int cur = -1;
    int rv[EW_C] = {0, 0, 0, 0}, cv[EW_C] = {0, 0, 0, 0};
    float px[EW_C] = {0, 0, 0, 0}, py[EW_C] = {0, 0, 0, 0};
    float qx[EW_C] = {0, 0, 0, 0}, qy[EW_C] = {0, 0, 0, 0};

    const int navail = min(EW_C, end - start);
#pragma unroll
    for (int i = 0; i < EW_C; ++i)
        if (i < navail) {
            int e = elist[start + i];
            rv[i] = ei[e]; cv[i] = ei[NEDGES + e];
        }
#pragma unroll
    for (int i = 0; i < EW_C; ++i)
        if (i < navail) {
            float2 p = *(const float2*)(PQ + (size_t)rv[i] * 256 + 2 * l);
            float2 q = *(const float2*)(PQ + (size_t)cv[i] * 256 + 128 + 2 * l);
            px[i] = p.x; py[i] = p.y; qx[i] = q.x; qy[i] = q.y;
        }

    for (int pos = start; pos < end; pos += EW_C) {
        const int cnt = min(EW_C, end - pos);
        int nn = end - (pos + EW_C);
        nn = nn < 0 ? 0 : (nn > EW_C ? EW_C : nn);
        int nrv[EW_C] = {0, 0, 0, 0}, ncv[EW_C] = {0, 0, 0, 0};
        float npx[EW_C] = {0, 0, 0, 0}, npy[EW_C] = {0, 0, 0, 0};
        float nqx[EW_C] = {0, 0, 0, 0}, nqy[EW_C] = {0, 0, 0, 0};
#pragma unroll
        for (int i = 0; i < EW_C; ++i)
            if (i < nn) {
                int e = elist[pos + EW_C + i];
                nrv[i] = ei[e]; ncv[i] = ei[NEDGES + e];
            }
#pragma unroll
        for (int i = 0; i < EW_C; ++i)
            if (i < nn) {
                float2 p = *(const float2*)(PQ + (size_t)nrv[i] * 256 + 2 * l);
                float2 q = *(const float2*)(PQ + (size_t)ncv[i] * 256 + 128 + 2 * l);
                npx[i] = p.x; npy[i] = p.y; nqx[i] = q.x; nqy[i] = q.y;
            }
#pragma unroll
        for (int i = 0; i < EW_C; ++i)
            if (i < cnt) {
                if (cv[i] != cur) {
                    if (cur >= 0) {
                        atomicAdd(Hsum + (size_t)cur * DD + 2 * l,     sx);
                        atomicAdd(Hsum + (size_t)cur * DD + 2 * l + 1, sy);
                    }
                    sx = 0.f; sy = 0.f; cur = cv[i];
                }
                sx += fmaxf(px[i] + qx[i], 0.f);
                sy += fmaxf(py[i] + qy[i], 0.f);
            }
#pragma unroll
        for (int i = 0; i < EW_C; ++i) {
            rv[i] = nrv[i]; cv[i] = ncv[i];
            px[i] = npx[i]; py[i] = npy[i]; qx[i] = nqx[i]; qy[i] = nqy[i];
        }
    }
    if (cur >= 0) {
        atomicAdd(Hsum + (size_t)cur * DD + 2 * l,     sx);
        atomicAdd(Hsum + (size_t)cur * DD + 2 * l + 1, sy);
    }
}

// Edge elementwise v2: packed (src,dst) sequential reads, EW_C2=8 pipeline.
#define EW_C2 8
__global__ __launch_bounds__(256)
void edge_ew2(const float* __restrict__ PQ, const int2* __restrict__ ep,
              float* Hsum) {
    const int t = threadIdx.x, w = t >> 6, l = t & 63;
    const int start = blockIdx.x * 512 + w * 128;
    if (start >= NEDGES) return;
    const int end = min(start + 128, NEDGES);

    float sx = 0.f, sy = 0.f;
    int cur = -1;
    int rv[EW_C2], cv[EW_C2];
    float px[EW_C2], py[EW_C2], qx[EW_C2], qy[EW_C2];
#pragma unroll
    for (int i = 0; i < EW_C2; ++i) {
        rv[i] = 0; cv[i] = 0; px[i] = 0.f; py[i] = 0.f; qx[i] = 0.f; qy[i] = 0.f;
    }

    const int navail = min(EW_C2, end - start);
#pragma unroll
    for (int i = 0; i < EW_C2; ++i)
        if (i < navail) {
            int2 e = ep[start + i];
            rv[i] = e.x; cv[i] = e.y;
        }
#pragma unroll
    for (int i = 0; i < EW_C2; ++i)
        if (i < navail) {
            float2 p = *(const float2*)(PQ + (size_t)rv[i] * 256 + 2 * l);
            float2 q = *(const float2*)(PQ + (size_t)cv[i] * 256 + 128 + 2 * l);
            px[i] = p.x; py[i] = p.y; qx[i] = q.x; qy[i] = q.y;
        }

    for (int pos = start; pos < end; pos += EW_C2) {
        const int cnt = min(EW_C2, end - pos);
        int nn = end - (pos + EW_C2);
        nn = nn < 0 ? 0 : (nn > EW_C2 ? EW_C2 : nn);
        int nrv[EW_C2], ncv[EW_C2];
        float npx[EW_C2], npy[EW_C2], nqx[EW_C2], nqy[EW_C2];
#pragma unroll
        for (int i = 0; i < EW_C2; ++i) {
            nrv[i] = 0; ncv[i] = 0; npx[i] = 0.f; npy[i] = 0.f;
            nqx[i] = 0.f; nqy[i] = 0.f;
        }
#pragma unroll
        for (int i = 0; i < EW_C2; ++i)
            if (i < nn) {
                int2 e = ep[pos + EW_C2 + i];
                nrv[i] = e.x; ncv[i] = e.y;
            }
#pragma unroll
        for (int i = 0; i < EW_C2; ++i)
            if (i < nn) {
                float2 p = *(const float2*)(PQ + (size_t)nrv[i] * 256 + 2 * l);
                float2 q = *(const float2*)(PQ + (size_t)ncv[i] * 256 + 128 + 2 * l);
                npx[i] = p.x; npy[i] = p.y; nqx[i] = q.x; nqy[i] = q.y;
            }
#pragma unroll
        for (int i = 0; i < EW_C2; ++i)
            if (i < cnt) {
                if (cv[i] != cur) {
                    if (cur >= 0) {
                        atomicAdd(Hsum + (size_t)cur * DD + 2 * l,     sx);
                        atomicAdd(Hsum + (size_t)cur * DD + 2 * l + 1, sy);
                    }
                    sx = 0.f; sy = 0.f; cur = cv[i];
                }
                sx += fmaxf(px[i] + qx[i], 0.f);
                sy += fmaxf(py[i] + qy[i], 0.f);
            }
#pragma unroll
        for (int i = 0; i < EW_C2; ++i) {
            rv[i] = nrv[i]; cv[i] = ncv[i];
            px[i] = npx[i]; py[i] = npy[i]; qx[i] = nqx[i]; qy[i] = nqy[i];
        }
    }
    if (cur >= 0) {
        atomicAdd(Hsum + (size_t)cur * DD + 2 * l,     sx);
        atomicAdd(Hsum + (size_t)cur * DD + 2 * l + 1, sy);
    }
}

// ---------------------------------------------------------------------------
// Fused node MLP (MFMA): out = relu( relu([x|Hsum]@Wn + ub1 + deg*vv) @ U2 + ub2 )
__device__ inline int hs_idx(int m, int j) {
    return m * 128 + ((((j >> 2) ^ (m & 31)) << 2) | (j & 3));
}

__global__ __launch_bounds__(256, 2)
void node_mfma(const float* __restrict__ x, float* outHsum,
               const ushort_t* __restrict__ wnp, const ushort_t* __restrict__ u2p,
               const int* __restrict__ deg, const float* __restrict__ vv,
               const float* __restrict__ ub1, const float* __restrict__ ub2) {
    __shared__ __align__(16) float    Hs[128 * 128];
    __shared__ __align__(16) ushort_t Wst[4096];
    const int t = threadIdx.x, w = t >> 6, l = t & 63;
    const int lh = l >> 5, ln = l & 31;
    const int base = blockIdx.x * 128;
    const int row = base + w * 32 + ln;
    const int rowc = min(row, NNODES - 1);
    const float* ax = x + (size_t)rowc * DD;
    const float* ah = outHsum + (size_t)rowc * DD;

    f32x16 acc[4];
#pragma unroll
    for (int tt = 0; tt < 4; ++tt)
#pragma unroll
        for (int q = 0; q < 16; ++q) acc[tt][q] = 0.f;

    float4 pfh = *(const float4*)(wnp + t * 8);
    float4 pfl = *(const float4*)(wnp + 2048 + t * 8);
    for (int u = 0; u < 16; ++u) {
        __syncthreads();
        *(float4*)(Wst + t * 8)        = pfh;
        *(float4*)(Wst + 2048 + t * 8) = pfl;
        const int k = u * 16 + lh * 8;
        const float* src = (k < 128) ? (ax + k) : (ah + (k - 128));
        float4 a0 = *(const float4*)(src);
        float4 a1 = *(const float4*)(src + 4);
        if (u < 15) {
            pfh = *(const float4*)(wnp + (u + 1) * 4096 + t * 8);
            pfl = *(const float4*)(wnp + (u + 1) * 4096 + 2048 + t * 8);
        }
        float av[8] = {a0.x, a0.y, a0.z, a0.w, a1.x, a1.y, a1.z, a1.w};
        bf16x8 a_hi, a_lo;
#pragma unroll
        for (int q = 0; q < 8; ++q) {
            ushort_t h, lo16;
            bf16_split(av[q], h, lo16);
            a_hi[q] = (short)h; a_lo[q] = (short)lo16;
        }
        __syncthreads();
#pragma unroll
        for (int tt = 0; tt < 4; ++tt) {
            const int boff = (lh * 128 + tt * 32 + ln) * 8;
            bf16x8 bh = *(const bf16x8*)(Wst + boff);
            bf16x8 bl = *(const bf16x8*)(Wst + 2048 + boff);
            acc[tt] = __builtin_amdgcn_mfma_f32_32x32x16_bf16(a_hi, bh, acc[tt], 0, 0, 0);
            acc[tt] = __builtin_amdgcn_mfma_f32_32x32x16_bf16(a_hi, bl, acc[tt], 0, 0, 0);
            acc[tt] = __builtin_amdgcn_mfma_f32_32x32x16_bf16(a_lo, bh, acc[tt], 0, 0, 0);
        }
    }

    float4 pfh2 = *(const float4*)(u2p + t * 8);
    float4 pfl2 = *(const float4*)(u2p + 2048 + t * 8);

    float b1v[4], vvv[4];
#pragma unroll
    for (int tt = 0; tt < 4; ++tt) {
        b1v[tt] = ub1[tt * 32 + ln];
        vvv[tt] = vv[tt * 32 + ln];
    }
#pragma unroll
    for (int tt = 0; tt < 4; ++tt) {
#pragma unroll
        for (int r = 0; r < 16; ++r) {
            int mrow = w * 32 + (r & 3) + 8 * (r >> 2) + 4 * lh;
            int n = min(base + mrow, NNODES - 1);
            float dg = (float)deg[n];
            float g = acc[tt][r] + b1v[tt] + dg * vvv[tt];
            Hs[hs_idx(mrow, tt * 32 + ln)] = fmaxf(g, 0.f);
            acc[tt][r] = 0.f;
        }
    }

    for (int u = 0; u < 8; ++u) {
        __syncthreads();
        *(float4*)(Wst + t * 8)        = pfh2;
        *(float4*)(Wst + 2048 + t * 8) = pfl2;
        if (u < 7) {
            pfh2 = *(const float4*)(u2p + (u + 1) * 4096 + t * 8);
            pfl2 = *(const float4*)(u2p + (u + 1) * 4096 + 2048 + t * 8);
        }
        __syncthreads();
        const int m  = w * 32 + ln;
        const int s0 = u * 4 + lh * 2;
        float4 f0 = *(const float4*)(Hs + m * 128 + (((s0    ) ^ ln) << 2));
        float4 f1 = *(const float4*)(Hs + m * 128 + (((s0 + 1) ^ ln) << 2));
        float fv[8] = {f0.x, f0.y, f0.z, f0.w, f1.x, f1.y, f1.z, f1.w};
        bf16x8 a_hi, a_lo;
#pragma unroll
        for (int q = 0; q < 8; ++q) {
            ushort_t h, lo16;
            bf16_split(fv[q], h, lo16);
            a_hi[q] = (short)h; a_lo[q] = (short)lo16;
        }
#pragma unroll
        for (int tt = 0; tt < 4; ++tt) {
            const int boff = (lh * 128 + tt * 32 + ln) * 8;
            bf16x8 bh = *(const bf16x8*)(Wst + boff);
            bf16x8 bl = *(const bf16x8*)(Wst + 2048 + boff);
            acc[tt] = __builtin_amdgcn_mfma_f32_32x32x16_bf16(a_hi, bh, acc[tt], 0, 0, 0);
            acc[tt] = __builtin_amdgcn_mfma_f32_32x32x16_bf16(a_hi, bl, acc[tt], 0, 0, 0);
            acc[tt] = __builtin_amdgcn_mfma_f32_32x32x16_bf16(a_lo, bh, acc[tt], 0, 0, 0);
        }
    }

    float b2v[4];
#pragma unroll
    for (int tt = 0; tt < 4; ++tt) b2v[tt] = ub2[tt * 32 + ln];
#pragma unroll
    for (int tt = 0; tt < 4; ++tt) {
#pragma unroll
        for (int r = 0; r < 16; ++r) {
            int mrow = w * 32 + (r & 3) + 8 * (r >> 2) + 4 * lh;
            int n = base + mrow;
            if (n < NNODES)
                outHsum[(size_t)n * DD + tt * 32 + ln] =
                    fmaxf(acc[tt][r] + b2v[tt], 0.f);
        }
    }
}

// ---------------------------------------------------------------------------
// FALLBACK MFMA edge kernel (rounds 3-5, proven)
template <int MODE>
__global__ __launch_bounds__(256, 2)
void edge_mfma(const ushort_t* __restrict__ xh, const ushort_t* __restrict__ xl,
               const ushort_t* __restrict__ w1p, const ushort_t* __restrict__ w2p,
               const int* __restrict__ ei, const int* __restrict__ elist,
               const float* __restrict__ b1, const float* __restrict__ b2,
               float* agg) {
    __shared__ __align__(16) float    Hsl[128 * 128];
    __shared__ __align__(16) ushort_t Wst[4096];
    const int t  = threadIdx.x;
    const int w  = t >> 6;
    const int l  = t & 63;
    const int lh = l >> 5;
    const int ln = l & 31;
    int eg;
    if (MODE == 1) eg = elist[blockIdx.x * EB + w * 32 + ln];
    else           eg = blockIdx.x * EB + w * 32 + ln;
    const int rv = ei[eg];
    const int cv = ei[NEDGES + eg];
    float bias1[4], bias2[4];
#pragma unroll
    for (int tt = 0; tt < 4; ++tt) {
        bias1[tt] = b1[tt * 32 + ln];
        bias2[tt] = b2[tt * 32 + ln];
    }
    f32x16 acc[4];
#pragma unroll
    for (int tt = 0; tt < 4; ++tt)
#pragma unroll
        for (int q = 0; q < 16; ++q) acc[tt][q] = 0.f;
    bf16x8 a_hi_next = *(const bf16x8*)(xh + (size_t)rv * DD + lh * 8);
    bf16x8 a_lo_next = *(const bf16x8*)(xl + (size_t)rv * DD + lh * 8);
    float4 pfh = *(const float4*)(w1p + t * 8);
    float4 pfl = *(const float4*)(w1p + 2048 + t * 8);
    for (int u = 0; u < 16; ++u) {
        __syncthreads();
        *(float4*)(Wst + t * 8)        = pfh;
        *(float4*)(Wst + 2048 + t * 8) = pfl;
        bf16x8 a_hi = a_hi_next, a_lo = a_lo_next;
        if (u < 15) {
            pfh = *(const float4*)(w1p + (u + 1) * 4096 + t * 8);
            pfl = *(const float4*)(w1p + (u + 1) * 4096 + 2048 + t * 8);
            int kk = (u + 1) * 16 + lh * 8;
            const int node = (kk < 128) ? rv : cv;
            const int off  = kk & 127;
            a_hi_next = *(const bf16x8*)(xh + (size_t)node * DD + off);
            a_lo_next = *(const bf16x8*)(xl + (size_t)node * DD + off);
        }
        __syncthreads();
#pragma unroll
        for (int tt = 0; tt < 4; ++tt) {
            const int boff = (lh * 128 + tt * 32 + ln) * 8;
            bf16x8 bh = *(const bf16x8*)(Wst + boff);
            bf16x8 bl = *(const bf16x8*)(Wst + 2048 + boff);
            acc[tt] = __builtin_amdgcn_mfma_f32_32x32x16_bf16(a_hi, bh, acc[tt], 0, 0, 0);
            acc[tt] = __builtin_amdgcn_mfma_f32_32x32x16_bf16(a_hi, bl, acc[tt], 0, 0, 0);
            acc[tt] = __builtin_amdgcn_mfma_f32_32x32x16_bf16(a_lo, bh, acc[tt], 0, 0, 0);
        }
    }
    pfh = *(const float4*)(w2p + t * 8);
    pfl = *(const float4*)(w2p + 2048 + t * 8);
#pragma unroll
    for (int tt = 0; tt < 4; ++tt) {
#pragma unroll
        for (int r = 0; r < 16; ++r) {
            int mrow = w * 32 + (r & 3) + 8 * (r >> 2) + 4 * lh;
            int j    = tt * 32 + ln;
            Hsl[hs_idx(mrow, j)] = fmaxf(acc[tt][r] + bias1[tt], 0.f);
            acc[tt][r] = 0.f;
        }
    }
    for (int u = 0; u < 8; ++u) {
        __syncthreads();
        *(float4*)(Wst + t * 8)        = pfh;
        *(float4*)(Wst + 2048 + t * 8) = pfl;
        if (u < 7) {
            pfh = *(const float4*)(w2p + (u + 1) * 4096 + t * 8);
            pfl = *(const float4*)(w2p + (u + 1) * 4096 + 2048 + t * 8);
        }
        __syncthreads();
        const int m  = w * 32 + ln;
        const int s0 = u * 4 + lh * 2;
        float4 f0 = *(const float4*)(Hsl + m * 128 + (((s0    ) ^ ln) << 2));
        float4 f1 = *(const float4*)(Hsl + m * 128 + (((s0 + 1) ^ ln) << 2));
        float fv[8] = {f0.x, f0.y, f0.z, f0.w, f1.x, f1.y, f1.z, f1.w};
        bf16x8 a_hi, a_lo;
#pragma unroll
        for (int q = 0; q < 8; ++q) {
            ushort_t h, lo16;
            bf16_split(fv[q], h, lo16);
            a_hi[q] = (short)h;
            a_lo[q] = (short)lo16;
        }
#pragma unroll
        for (int tt = 0; tt < 4; ++tt) {
            const int boff = (lh * 128 + tt * 32 + ln) * 8;
            bf16x8 bh = *(const bf16x8*)(Wst + boff);
            bf16x8 bl = *(const bf16x8*)(Wst + 2048 + boff);
            acc[tt] = __builtin_amdgcn_mfma_f32_32x32x16_bf16(a_hi, bh, acc[tt], 0, 0, 0);
            acc[tt] = __builtin_amdgcn_mfma_f32_32x32x16_bf16(a_hi, bl, acc[tt], 0, 0, 0);
            acc[tt] = __builtin_amdgcn_mfma_f32_32x32x16_bf16(a_lo, bh, acc[tt], 0, 0, 0);
        }
    }
    if (MODE == 1) {
        float s[4] = {0.f, 0.f, 0.f, 0.f};
        int cur = __shfl(cv, 0, 64);
#pragma unroll
        for (int row = 0; row < 32; ++row) {
            const int r = (row & 3) | ((row >> 3) << 2);
            const int h = (row >> 2) & 1;
            int nd = __shfl(cv, row, 64);
            if (nd != cur) {
                if (lh == 0) {
#pragma unroll
                    for (int tt = 0; tt < 4; ++tt)
                        atomicAdd(agg + (size_t)cur * DD + tt * 32 + ln, s[tt]);
                }
#pragma unroll
                for (int tt = 0; tt < 4; ++tt) s[tt] = 0.f;
                cur = nd;
            }
#pragma unroll
            for (int tt = 0; tt < 4; ++tt) {
                float mine  = acc[tt][r];
                float other = __shfl_xor(mine, 32, 64);
                float v = (h == lh) ? mine : other;
                s[tt] += v + bias2[tt];
            }
        }
        if (lh == 0) {
#pragma unroll
            for (int tt = 0; tt < 4; ++tt)
                atomicAdd(agg + (size_t)cur * DD + tt * 32 + ln, s[tt]);
        }
    } else {
        int cn[16];
#pragma unroll
        for (int r = 0; r < 16; ++r) {
            int mr = (r & 3) + 8 * (r >> 2) + 4 * lh;
            cn[r] = __shfl(cv, mr, 64);
        }
#pragma unroll
        for (int tt = 0; tt < 4; ++tt) {
#pragma unroll
            for (int r = 0; r < 16; ++r) {
                atomicAdd(agg + (size_t)cn[r] * DD + tt * 32 + ln,
                          acc[tt][r] + bias2[tt]);
            }
        }
    }
}

#define TE 64
#define KT 16
#define AX_S 260
#define HS_S 132
#define AX_WORDS (TE * AX_S)
#define WT_WORDS (KT * DD)
#define SMEM_WORDS (AX_WORDS + WT_WORDS + TE)

__global__ __launch_bounds__(256, 2)
void node_kernel(const float* __restrict__ x,
                 float* aggout,
                 const float* __restrict__ U1, const float* __restrict__ c1,
                 const float* __restrict__ U2, const float* __restrict__ c2) {
    __shared__ float smem[SMEM_WORDS];
    float* Ax = smem;
    float* Hss = smem;
    float* Wt = smem + AX_WORDS;
    const int t = threadIdx.x;
    const int base = blockIdx.x * TE;
    {
        const int e = t & 63;
        const int q = t >> 6;
        const int n = base + e;
        const bool valid = n < NNODES;
        const float* s1 = x + (size_t)n * DD;
        const float* s2 = aggout + (size_t)n * DD;
#pragma unroll
        for (int ci = 0; ci < 16; ++ci) {
            const int k4 = ci * 4 + q;
            float4 v = make_float4(0.f, 0.f, 0.f, 0.f);
            if (valid) {
                if (k4 < 32) v = *(const float4*)(s1 + k4 * 4);
                else         v = *(const float4*)(s2 + (k4 - 32) * 4);
            }
            *(float4*)(Ax + e * AX_S + k4 * 4) = v;
        }
    }
    const int jg = t & 31;
    const int eg2 = t >> 5;
    const int j0 = jg * 4;
    const float4 b1v = *(const float4*)(c1 + j0);
    const float4 b2v = *(const float4*)(c2 + j0);
    float acc[8][4];
#pragma unroll
    for (int i = 0; i < 8; ++i)
        acc[i][0] = acc[i][1] = acc[i][2] = acc[i][3] = 0.f;
    for (int kb = 0; kb < 256 / KT; ++kb) {
        __syncthreads();
        {
            const float* src = U1 + kb * KT * DD;
#pragma unroll
            for (int u = 0; u < 2; ++u) {
                const int f4i = u * 256 + t;
                *(float4*)(Wt + f4i * 4) = *(const float4*)(src + f4i * 4);
            }
        }
        __syncthreads();
        float4 Bc[KT];
#pragma unroll
        for (int kk = 0; kk < KT; ++kk)
            Bc[kk] = *(const float4*)(Wt + kk * DD + j0);
#pragma unroll
        for (int i = 0; i < 8; ++i) {
            const float* arow = Ax + (i * 8 + eg2) * AX_S + kb * KT;
            float a[KT];
#pragma unroll
            for (int kc = 0; kc < KT / 4; ++kc) {
                const float4 av = *(const float4*)(arow + kc * 4);
                a[kc * 4 + 0] = av.x; a[kc * 4 + 1] = av.y;
                a[kc * 4 + 2] = av.z; a[kc * 4 + 3] = av.w;
            }
#pragma unroll
            for (int kk = 0; kk < KT; ++kk) {
                acc[i][0] = fmaf(a[kk], Bc[kk].x, acc[i][0]);
                acc[i][1] = fmaf(a[kk], Bc[kk].y, acc[i][1]);
                acc[i][2] = fmaf(a[kk], Bc[kk].z, acc[i][2]);
                acc[i][3] = fmaf(a[kk], Bc[kk].w, acc[i][3]);
            }
        }
    }
    __syncthreads();
#pragma unroll
    for (int i = 0; i < 8; ++i) {
        float4 h;
        h.x = fmaxf(acc[i][0] + b1v.x, 0.f);
        h.y = fmaxf(acc[i][1] + b1v.y, 0.f);
        h.z = fmaxf(acc[i][2] + b1v.z, 0.f);
        h.w = fmaxf(acc[i][3] + b1v.w, 0.f);
        *(float4*)(Hss + (i * 8 + eg2) * HS_S + j0) = h;
        acc[i][0] = acc[i][1] = acc[i][2] = acc[i][3] = 0.f;
    }
    for (int kb = 0; kb < DD / KT; ++kb) {
        __syncthreads();
        {
            const float* src = U2 + kb * KT * DD;
#pragma unroll
            for (int u = 0; u < 2; ++u) {
                const int f4i = u * 256 + t;
                *(float4*)(Wt + f4i * 4) = *(const float4*)(src + f4i * 4);
            }
        }
        __syncthreads();
        float4 Bc[KT];
#pragma unroll
        for (int kk = 0; kk < KT; ++kk)
            Bc[kk] = *(const float4*)(Wt + kk * DD + j0);
#pragma unroll
        for (int i = 0; i < 8; ++i) {
            const float* arow = Hss + (i * 8 + eg2) * HS_S + kb * KT;
            float a[KT];
#pragma unroll
            for (int kc = 0; kc < KT / 4; ++kc) {
                const float4 av = *(const float4*)(arow + kc * 4);
                a[kc * 4 + 0] = av.x; a[kc * 4 + 1] = av.y;
                a[kc * 4 + 2] = av.z; a[kc * 4 + 3] = av.w;
            }
#pragma unroll
            for (int kk = 0; kk < KT; ++kk) {
                acc[i][0] = fmaf(a[kk], Bc[kk].x, acc[i][0]);
                acc[i][1] = fmaf(a[kk], Bc[kk].y, acc[i][1]);
                acc[i][2] = fmaf(a[kk], Bc[kk].z, acc[i][2]);
                acc[i][3] = fmaf(a[kk], Bc[kk].w, acc[i][3]);
            }
        }
    }
#pragma unroll
    for (int i = 0; i < 8; ++i) {
        const int n = base + i * 8 + eg2;
        if (n < NNODES) {
            float4 o;
            o.x = fmaxf(acc[i][0] + b2v.x, 0.f);
            o.y = fmaxf(acc[i][1] + b2v.y, 0.f);
            o.z = fmaxf(acc[i][2] + b2v.z, 0.f);
            o.w = fmaxf(acc[i][3] + b2v.w, 0.f);
            *(float4*)(aggout + (size_t)n * DD + j0) = o;
        }
    }
}

// ---------------------------------------------------------------------------
extern "C" void kernel_launch(void* const* d_in, const int* in_sizes, int n_in,
                              void* d_out, int out_size, void* d_ws, size_t ws_size,
                              hipStream_t stream) {
    const float* x   = (const float*)d_in[0];
    const int*   ei  = (const int*)d_in[1];
    const float* mW1 = (const float*)d_in[2];
    const float* mb1 = (const float*)d_in[3];
    const float* mW2 = (const float*)d_in[4];
    const float* mb2 = (const float*)d_in[5];
    const float* uW1 = (const float*)d_in[6];
    const float* ub1 = (const float*)d_in[7];
    const float* uW2 = (const float*)d_in[8];
    const float* ub2 = (const float*)d_in[9];
    float* out = (float*)d_out;   // aggregation buffer + final output

    const int n4 = NNODES * DD / 4;

    if (ws_size >= (size_t)WS_NEW) {
        float*    PQ   = (float*)((char*)d_ws + PQ_OFF2);
        ushort_t* w1p  = (ushort_t*)((char*)d_ws + W1P_OFF2);
        ushort_t* u2p  = (ushort_t*)((char*)d_ws + U2P_OFF2);
        ushort_t* wnp  = (ushort_t*)((char*)d_ws + WNP_OFF2);
        float*    W2U  = (float*)((char*)d_ws + W2U_OFF2);
        float*    vv   = (float*)((char*)d_ws + VV_OFF2);
        int*      deg  = (int*)((char*)d_ws + DEG_OFF2);
        int*      curb = (int*)((char*)d_ws + CUR_OFF2);
        int*      bsum = (int*)((char*)d_ws + BSUM_OFF2);

        if (ws_size >= (size_t)WS_NEW2) {
            // ------- epair path: 11 launches -------
            int2* ep = (int2*)((char*)d_ws + EL_OFF2);
            zero_all<<<(1612512 + 255) / 256, 256, 0, stream>>>(
                (float4*)out, (int4*)deg);
            hist_kernel<<<(NEDGES + 255) / 256, 256, 0, stream>>>(ei, deg);
            scanA<<<NB_SCAN, 1024, 0, stream>>>(deg, curb, bsum);
            scanC2<<<NB_SCAN, 1024, 0, stream>>>(deg, curb, bsum);
            fill2_kernel<<<(NEDGES + 255) / 256, 256, 0, stream>>>(ei, curb, ep);
            pack3<<<256, 256, 0, stream>>>(mW1, uW2, uW1, w1p, u2p, wnp);
            w2u_vv<<<65, 256, 0, stream>>>(mW2, mb2, uW1, W2U, vv);
            pack_w<<<(128 * 128 + 255) / 256, 256, 0, stream>>>(W2U, wnp + 32768, 128);
            pq_gemm<<<dim3(391, 2), 256, 0, stream>>>(x, w1p, mb1, PQ);
            edge_ew2<<<(NEDGES + 511) / 512, 256, 0, stream>>>(PQ, ep, out);
            node_mfma<<<391, 256, 0, stream>>>(x, out, wnp, u2p, deg, vv, ub1, ub2);
        } else {
            // ------- round-7 proven path -------
            int* elst = (int*)((char*)d_ws + EL_OFF2);
            zero_kernel<<<(n4 + 255) / 256, 256, 0, stream>>>((float4*)out, n4);
            zero_i32<<<(50048 + 255) / 256, 256, 0, stream>>>(deg, 50048);
            hist_kernel<<<(NEDGES + 255) / 256, 256, 0, stream>>>(ei, deg);
            scanA<<<NB_SCAN, 1024, 0, stream>>>(deg, curb, bsum);
            scanB<<<1, 64, 0, stream>>>(bsum, NB_SCAN);
            scanC<<<NB_SCAN, 1024, 0, stream>>>(deg, curb, bsum);
            fill_kernel<<<(NEDGES + 255) / 256, 256, 0, stream>>>(ei, curb, elst);
            pack_w<<<(256 * 128 + 255) / 256, 256, 0, stream>>>(mW1, w1p, 256);
            pack_w<<<(128 * 128 + 255) / 256, 256, 0, stream>>>(uW2, u2p, 128);
            w2u_kernel<<<64, 256, 0, stream>>>(mW2, uW1, W2U);
            vvec_kernel<<<1, 128, 0, stream>>>(mb2, uW1, vv);
            pack_w<<<(128 * 128 + 255) / 256, 256, 0, stream>>>(uW1, wnp, 128);
            pack_w<<<(128 * 128 + 255) / 256, 256, 0, stream>>>(W2U, wnp + 32768, 128);
            pq_gemm<<<dim3(391, 2), 256, 0, stream>>>(x, w1p, mb1, PQ);
            edge_ew<<<(NEDGES + 511) / 512, 256, 0, stream>>>(PQ, ei, elst, out);
            node_mfma<<<391, 256, 0, stream>>>(x, out, wnp, u2p, deg, vv, ub1, ub2);
        }
        return;
    }

    // ---------------- fallback paths (rounds 2-5, proven) ----------------
    zero_kernel<<<(n4 + 255) / 256, 256, 0, stream>>>((float4*)out, n4);
    if (ws_size >= (size_t)WS_MIN) {
        ushort_t* xh  = (ushort_t*)((char*)d_ws + XH_OFF);
        ushort_t* xl  = (ushort_t*)((char*)d_ws + XL_OFF);
        ushort_t* w1p = (ushort_t*)((char*)d_ws + W1P_OFF);
        ushort_t* w2p = (ushort_t*)((char*)d_ws + W2P_OFF);
        pack_x<<<(NNODES * DD + 255) / 256, 256, 0, stream>>>(x, xh, xl);
        pack_w<<<(256 * 128 + 255) / 256, 256, 0, stream>>>(mW1, w1p, 256);
        pack_w<<<(128 * 128 + 255) / 256, 256, 0, stream>>>(mW2, w2p, 128);
        if (ws_size >= (size_t)WS_CSR) {
            int* deg    = (int*)((char*)d_ws + DEG_OFF);
            int* elist  = (int*)((char*)d_ws + ELIST_OFF);
            int* cursor = (int*)((char*)d_ws + CUR_OFF);
            zero_i32<<<(50048 + 255) / 256, 256, 0, stream>>>(deg, 50048);
            hist_kernel<<<(NEDGES + 255) / 256, 256, 0, stream>>>(ei, deg);
            scan_kernel<<<1, 1024, 0, stream>>>(deg, cursor);
            fill_kernel<<<(NEDGES + 255) / 256, 256, 0, stream>>>(ei, cursor, elist);
            edge_mfma<1><<<NEDGES / EB, 256, 0, stream>>>(
                xh, xl, w1p, w2p, ei, elist, mb1, mb2, out);
        } else {
            edge_mfma<0><<<NEDGES / EB, 256, 0, stream>>>(
                xh, xl, w1p, w2p, ei, (const int*)nullptr, mb1, mb2, out);
        }
    }
    node_kernel<<<(NNODES + TE - 1) / TE, 256, 0, stream>>>(x, out, uW1, ub1,
                                                            uW2, ub2);
}

// Round 10
// 322.028 us; speedup vs baseline: 1.3317x; 1.3317x over previous
//
#include <hip/hip_runtime.h>
#include <stdint.h>

typedef unsigned short ushort_t;

#define NNODES 50000
#define NEDGES 800000
#define DD 128
#define EB 128                     // edges per block (fallback MFMA path)

typedef short bf16x8 __attribute__((ext_vector_type(8)));
typedef float f32x16 __attribute__((ext_vector_type(16)));

// ---------------- fallback ws layout (bytes) — rounds 3-5, proven ----------
#define XH_OFF    0u
#define XL_OFF    12800000u
#define W1P_OFF   25600000u
#define W2P_OFF   25731072u
#define WS_MIN    25796608u
#define DEG_OFF   25796608u
#define ELIST_OFF 25996800u
#define CUR_OFF   29196800u
#define WS_CSR    29396992u

// ---------------- factored-path ws layout (bytes) ----------------
#define PQ_OFF2   0u                    // 50000*256*4 = 51,200,000
#define W1P_OFF2  51200000u             // 131072
#define U2P_OFF2  51331072u             // 65536
#define WNP_OFF2  51396608u             // 131072
#define W2U_OFF2  51527680u             // 65536
#define VV_OFF2   51593216u             // 512
#define DEG_OFF2  51593728u             // 200192
#define CUR_OFF2  51793920u             // 200192
#define BSUM_OFF2 51994112u             // 256
#define EL_OFF2   51994368u             // 3,200,000 (elist) or 6,400,000 (epair)
#define WS_NEW    55194368u             // round-7 proven path
#define WS_NEW2   58394368u             // epair path (int2[800000])

#define NB_SCAN 49                      // ceil(50000/1024)

// ---------------------------------------------------------------------------
__global__ void zero_kernel(float4* __restrict__ p, int n4) {
    int i = blockIdx.x * blockDim.x + threadIdx.x;
    if (i < n4) p[i] = make_float4(0.f, 0.f, 0.f, 0.f);
}
__global__ void zero_i32(int* __restrict__ p, int n) {
    int i = blockIdx.x * blockDim.x + threadIdx.x;
    if (i < n) p[i] = 0;
}

__device__ inline void bf16_split(float f, ushort_t& hi, ushort_t& lo) {
    uint32_t b = __float_as_uint(f);
    uint32_t hb = b & 0xFFFF0000u;
    hi = (ushort_t)(b >> 16);
    float lof = f - __uint_as_float(hb);
    lo = (ushort_t)(__float_as_uint(lof) >> 16);
}

__global__ void pack_x(const float* __restrict__ x,
                       ushort_t* __restrict__ xh, ushort_t* __restrict__ xl) {
    int i = blockIdx.x * blockDim.x + threadIdx.x;
    if (i >= NNODES * DD) return;
    ushort_t h, l;
    bf16_split(x[i], h, l);
    xh[i] = h; xl[i] = l;
}

// Pack W [K][128] -> per-ktile fragment order, hi plane then lo plane.
__global__ void pack_w(const float* __restrict__ W, ushort_t* __restrict__ wp,
                       int K) {
    int i = blockIdx.x * blockDim.x + threadIdx.x;
    if (i >= K * 128) return;
    int k = i >> 7, n = i & 127;
    int base = (k >> 4) * 4096 + ((((k >> 3) & 1) * 128 + n) << 3) + (k & 7);
    ushort_t h, l;
    bf16_split(W[i], h, l);
    wp[base] = h; wp[base + 2048] = l;
}

// fused pack of mW1 (K=256) + uW2 (K=128) + uW1-top (K=128) in one launch
__global__ void pack3(const float* __restrict__ mW1, const float* __restrict__ uW2,
                      const float* __restrict__ uW1,
                      ushort_t* __restrict__ w1p, ushort_t* __restrict__ u2p,
                      ushort_t* __restrict__ wnp) {
    int i = blockIdx.x * blockDim.x + threadIdx.x;   // 0..65535
    const float* W; ushort_t* wp; int li;
    if (i < 32768)      { W = mW1; wp = w1p; li = i; }
    else if (i < 49152) { W = uW2; wp = u2p; li = i - 32768; }
    else                { W = uW1; wp = wnp; li = i - 49152; }
    int k = li >> 7, n = li & 127;
    int base = (k >> 4) * 4096 + ((((k >> 3) & 1) * 128 + n) << 3) + (k & 7);
    ushort_t h, l;
    bf16_split(W[li], h, l);
    wp[base] = h; wp[base + 2048] = l;
}

// ---------------- CSR build ----------------
__global__ void hist_kernel(const int* __restrict__ ei, int* __restrict__ deg) {
    int i = blockIdx.x * blockDim.x + threadIdx.x;
    if (i < NEDGES) atomicAdd(&deg[ei[NEDGES + i]], 1);
}

// single-block scan (fallback path only)
__global__ __launch_bounds__(1024)
void scan_kernel(const int* __restrict__ deg, int* __restrict__ cursor) {
    __shared__ int part[1024];
    const int t = threadIdx.x;
    const int CH = 49;
    int s = 0;
#pragma unroll 1
    for (int i = 0; i < CH; ++i) {
        int idx = t * CH + i;
        if (idx < NNODES) s += deg[idx];
    }
    part[t] = s;
    __syncthreads();
    for (int d = 1; d < 1024; d <<= 1) {
        int v = (t >= d) ? part[t - d] : 0;
        __syncthreads();
        part[t] += v;
        __syncthreads();
    }
    int run = (t == 0) ? 0 : part[t - 1];
#pragma unroll 1
    for (int i = 0; i < CH; ++i) {
        int idx = t * CH + i;
        if (idx < NNODES) {
            cursor[idx] = run;
            run += deg[idx];
        }
    }
}

// parallel scan
__global__ __launch_bounds__(1024)
void scanA(const int* __restrict__ deg, int* __restrict__ cur,
           int* __restrict__ bsum) {
    __shared__ int sm[1024];
    const int t = threadIdx.x;
    const int idx = blockIdx.x * 1024 + t;
    int d = (idx < NNODES) ? deg[idx] : 0;
    sm[t] = d;
    __syncthreads();
    for (int off = 1; off < 1024; off <<= 1) {
        int v = 0;
        if (t >= off) v = sm[t - off];
        __syncthreads();
        sm[t] += v;
        __syncthreads();
    }
    if (idx < NNODES) cur[idx] = sm[t];          // inclusive within block
    if (t == 1023) bsum[blockIdx.x] = sm[1023];  // raw block sum
}
__global__ void scanB(int* __restrict__ bsum, int nb) {
    if (threadIdx.x == 0) {
        int run = 0;
        for (int i = 0; i < nb; ++i) { int v = bsum[i]; bsum[i] = run; run += v; }
    }
}
__global__ __launch_bounds__(1024)
void scanC(const int* __restrict__ deg, int* __restrict__ cur,
           const int* __restrict__ bsum) {
    const int idx = blockIdx.x * 1024 + threadIdx.x;
    if (idx < NNODES) cur[idx] = cur[idx] - deg[idx] + bsum[blockIdx.x];
}
// scanC with scanB folded in (bsum holds RAW block sums)
__global__ __launch_bounds__(1024)
void scanC2(const int* __restrict__ deg, int* __restrict__ cur,
            const int* __restrict__ bsum) {
    int pre = 0;
#pragma unroll 1
    for (int j = 0; j < blockIdx.x; ++j) pre += bsum[j];
    const int idx = blockIdx.x * 1024 + threadIdx.x;
    if (idx < NNODES) cur[idx] = cur[idx] - deg[idx] + pre;
}

__global__ void fill_kernel(const int* __restrict__ ei, int* __restrict__ cursor,
                            int* __restrict__ elist) {
    int i = blockIdx.x * blockDim.x + threadIdx.x;
    if (i < NEDGES) {
        int pos = atomicAdd(&cursor[ei[NEDGES + i]], 1);
        elist[pos] = i;
    }
}
// fill packed (src,dst) pairs in dest-sorted order
__global__ void fill2_kernel(const int* __restrict__ ei, int* __restrict__ cursor,
                             int2* __restrict__ ep) {
    int i = blockIdx.x * blockDim.x + threadIdx.x;
    if (i < NEDGES) {
        int c = ei[NEDGES + i];
        int pos = atomicAdd(&cursor[c], 1);
        ep[pos] = make_int2(ei[i], c);
    }
}

// ---------------- small precomputes ----------------
__global__ void w2u_kernel(const float* __restrict__ W2,
                           const float* __restrict__ U1, float* __restrict__ W2U) {
    int id = blockIdx.x * 256 + threadIdx.x;
    if (id >= 128 * 128) return;
    int i = id >> 7, j = id & 127;
    float s = 0.f;
    for (int k = 0; k < 128; ++k) s += W2[i * 128 + k] * U1[(128 + k) * 128 + j];
    W2U[id] = s;
}
__global__ void vvec_kernel(const float* __restrict__ b2,
                            const float* __restrict__ U1, float* __restrict__ vv) {
    int j = threadIdx.x;
    if (j >= 128) return;
    float s = 0.f;
    for (int k = 0; k < 128; ++k) s += b2[k] * U1[(128 + k) * 128 + j];
    vv[j] = s;
}
// fused W2U + vv (grid 65: blocks 0..63 = W2U, block 64 = vv)
__global__ void w2u_vv(const float* __restrict__ W2, const float* __restrict__ b2,
                       const float* __restrict__ U1,
                       float* __restrict__ W2U, float* __restrict__ vv) {
    if (blockIdx.x < 64) {
        int id = blockIdx.x * 256 + threadIdx.x;
        int i = id >> 7, j = id & 127;
        float s = 0.f;
        for (int k = 0; k < 128; ++k)
            s += W2[i * 128 + k] * U1[(128 + k) * 128 + j];
        W2U[id] = s;
    } else if (threadIdx.x < 128) {
        int j = threadIdx.x;
        float s = 0.f;
        for (int k = 0; k < 128; ++k)
            s += b2[k] * U1[(128 + k) * 128 + j];
        vv[j] = s;
    }
}

// ---------------------------------------------------------------------------
// PQ GEMM: PQ[n][0:128] = x[n]@W1t + b1 ; PQ[n][128:256] = x[n]@W1b
__global__ __launch_bounds__(256)
void pq_gemm(const float* __restrict__ x, const ushort_t* __restrict__ w1p,
             const float* __restrict__ b1, float* __restrict__ PQ) {
    __shared__ __align__(16) ushort_t Wst[4096];
    const int t = threadIdx.x, w = t >> 6, l = t & 63;
    const int lh = l >> 5, ln = l & 31;
    const int base = blockIdx.x * 128;
    const int c = blockIdx.y;
    const int row = base + w * 32 + ln;
    const float* ax = x + (size_t)min(row, NNODES - 1) * DD;
    const ushort_t* wt = w1p + c * 8 * 4096;

    f32x16 acc[4];
#pragma unroll
    for (int tt = 0; tt < 4; ++tt)
#pragma unroll
        for (int q = 0; q < 16; ++q) acc[tt][q] = 0.f;

    float4 pfh = *(const float4*)(wt + t * 8);
    float4 pfl = *(const float4*)(wt + 2048 + t * 8);
    for (int u = 0; u < 8; ++u) {
        __syncthreads();
        *(float4*)(Wst + t * 8)        = pfh;
        *(float4*)(Wst + 2048 + t * 8) = pfl;
        float4 a0 = *(const float4*)(ax + u * 16 + lh * 8);
        float4 a1 = *(const float4*)(ax + u * 16 + lh * 8 + 4);
        if (u < 7) {
            pfh = *(const float4*)(wt + (u + 1) * 4096 + t * 8);
            pfl = *(const float4*)(wt + (u + 1) * 4096 + 2048 + t * 8);
        }
        float av[8] = {a0.x, a0.y, a0.z, a0.w, a1.x, a1.y, a1.z, a1.w};
        bf16x8 a_hi, a_lo;
#pragma unroll
        for (int q = 0; q < 8; ++q) {
            ushort_t h, lo16;
            bf16_split(av[q], h, lo16);
            a_hi[q] = (short)h; a_lo[q] = (short)lo16;
        }
        __syncthreads();
#pragma unroll
        for (int tt = 0; tt < 4; ++tt) {
            const int boff = (lh * 128 + tt * 32 + ln) * 8;
            bf16x8 bh = *(const bf16x8*)(Wst + boff);
            bf16x8 bl = *(const bf16x8*)(Wst + 2048 + boff);
            acc[tt] = __builtin_amdgcn_mfma_f32_32x32x16_bf16(a_hi, bh, acc[tt], 0, 0, 0);
            acc[tt] = __builtin_amdgcn_mfma_f32_32x32x16_bf16(a_hi, bl, acc[tt], 0, 0, 0);
            acc[tt] = __builtin_amdgcn_mfma_f32_32x32x16_bf16(a_lo, bh, acc[tt], 0, 0, 0);
        }
    }
    float bias[4];
#pragma unroll
    for (int tt = 0; tt < 4; ++tt)
        bias[tt] = (c == 0) ? b1[tt * 32 + ln] : 0.f;
#pragma unroll
    for (int tt = 0; tt < 4; ++tt) {
#pragma unroll
        for (int r = 0; r < 16; ++r) {
            int mrow = w * 32 + (r & 3) + 8 * (r >> 2) + 4 * lh;
            int n = base + mrow;
            if (n < NNODES)
                PQ[(size_t)n * 256 + c * 128 + tt * 32 + ln] = acc[tt][r] + bias[tt];
        }
    }
}

// ---------------------------------------------------------------------------
// Edge elementwise (round-7 proven fallback: elist indirection, EW_C=4, atomics)
#define EW_C 4
__global__ __launch_bounds__(256)
void edge_ew(const float* __restrict__ PQ, const int* __restrict__ ei,
             const int* __restrict__ elist, float* Hsum) {
    const int t = threadIdx.x, w = t >> 6, l = t & 63;
    const int start = blockIdx.x * 512 + w * 128;
    if (start >= NEDGES) return;
    const int end = min(start + 128, NEDGES);

    float sx = 0.f, sy = 0.f;
    int cur = -1;
    int rv[EW_C] = {0, 0, 0, 0}, cv[EW_C] = {0, 0, 0, 0};
    float px[EW_C] = {0, 0, 0, 0}, py[EW_C] = {0, 0, 0, 0};
    float qx[EW_C] = {0, 0, 0, 0}, qy[EW_C] = {0, 0, 0, 0};

    const int navail = min(EW_C, end - start);
#pragma unroll
    for (int i = 0; i < EW_C; ++i)
        if (i < navail) {
            int e = elist[start + i];
            rv[i] = ei[e]; cv[i] = ei[NEDGES + e];
        }
#pragma unroll
    for (int i = 0; i < EW_C; ++i)
        if (i < navail) {
            float2 p = *(const float2*)(PQ + (size_t)rv[i] * 256 + 2 * l);
            float2 q = *(const float2*)(PQ + (size_t)cv[i] * 256 + 128 + 2 * l);
            px[i] = p.x; py[i] = p.y; qx[i] = q.x; qy[i] = q.y;
        }

    for (int pos = start; pos < end; pos += EW_C) {
        const int cnt = min(EW_C, end - pos);
        int nn = end - (pos + EW_C);
        nn = nn < 0 ? 0 : (nn > EW_C ? EW_C : nn);
        int nrv[EW_C] = {0, 0, 0, 0}, ncv[EW_C] = {0, 0, 0, 0};
        float npx[EW_C] = {0, 0, 0, 0}, npy[EW_C] = {0, 0, 0, 0};
        float nqx[EW_C] = {0, 0, 0, 0}, nqy[EW_C] = {0, 0, 0, 0};
#pragma unroll
        for (int i = 0; i < EW_C; ++i)
            if (i < nn) {
                int e = elist[pos + EW_C + i];
                nrv[i] = ei[e]; ncv[i] = ei[NEDGES + e];
            }
#pragma unroll
        for (int i = 0; i < EW_C; ++i)
            if (i < nn) {
                float2 p = *(const float2*)(PQ + (size_t)nrv[i] * 256 + 2 * l);
                float2 q = *(const float2*)(PQ + (size_t)ncv[i] * 256 + 128 + 2 * l);
                npx[i] = p.x; npy[i] = p.y; nqx[i] = q.x; nqy[i] = q.y;
            }
#pragma unroll
        for (int i = 0; i < EW_C; ++i)
            if (i < cnt) {
                if (cv[i] != cur) {
                    if (cur >= 0) {
                        atomicAdd(Hsum + (size_t)cur * DD + 2 * l,     sx);
                        atomicAdd(Hsum + (size_t)cur * DD + 2 * l + 1, sy);
                    }
                    sx = 0.f; sy = 0.f; cur = cv[i];
                }
                sx += fmaxf(px[i] + qx[i], 0.f);
                sy += fmaxf(py[i] + qy[i], 0.f);
            }
#pragma unroll
        for (int i = 0; i < EW_C; ++i) {
            rv[i] = nrv[i]; cv[i] = ncv[i];
            px[i] = npx[i]; py[i] = npy[i]; qx[i] = nqx[i]; qy[i] = nqy[i];
        }
    }
    if (cur >= 0) {
        atomicAdd(Hsum + (size_t)cur * DD + 2 * l,     sx);
        atomicAdd(Hsum + (size_t)cur * DD + 2 * l + 1, sy);
    }
}

// ---------------------------------------------------------------------------
// Edge per-node: wave w owns dest node n; streams its CSR run of ep,
// accumulates relu(P[src]+Q[n]) in regs, ONE plain store. No atomics,
// no out-zero needed. endp = cursor after fill2 (= row end); start = end-deg.
__global__ __launch_bounds__(256)
void edge_pn(const float* __restrict__ PQ, const int2* __restrict__ ep,
             const int* __restrict__ endp, const int* __restrict__ deg,
             float* __restrict__ Hsum) {
    const int n = blockIdx.x * 4 + (threadIdx.x >> 6);
    if (n >= NNODES) return;
    const int l = threadIdx.x & 63;
    const int end = endp[n];
    const int start = end - deg[n];

    const float2 q = *(const float2*)(PQ + (size_t)n * 256 + 128 + 2 * l);
    float sx = 0.f, sy = 0.f;

    // depth-4 chunked pipeline: prefetch next chunk's srcs+P while consuming
    int s0[4];
    float2 p0[4];
    const int c0 = min(4, end - start);
#pragma unroll
    for (int i = 0; i < 4; ++i) s0[i] = (i < c0) ? ep[start + i].x : 0;
#pragma unroll
    for (int i = 0; i < 4; ++i)
        if (i < c0) p0[i] = *(const float2*)(PQ + (size_t)s0[i] * 256 + 2 * l);

    for (int e = start; e < end; e += 4) {
        const int cnt = min(4, end - e);
        int nn = end - (e + 4);
        nn = nn < 0 ? 0 : (nn > 4 ? 4 : nn);
        int s1[4];
        float2 p1[4];
#pragma unroll
        for (int i = 0; i < 4; ++i) s1[i] = (i < nn) ? ep[e + 4 + i].x : 0;
#pragma unroll
        for (int i = 0; i < 4; ++i)
            if (i < nn) p1[i] = *(const float2*)(PQ + (size_t)s1[i] * 256 + 2 * l);
#pragma unroll
        for (int i = 0; i < 4; ++i)
            if (i < cnt) {
                sx += fmaxf(p0[i].x + q.x, 0.f);
                sy += fmaxf(p0[i].y + q.y, 0.f);
            }
#pragma unroll
        for (int i = 0; i < 4; ++i) { s0[i] = s1[i]; p0[i] = p1[i]; }
    }

    Hsum[(size_t)n * DD + 2 * l]     = sx;
    Hsum[(size_t)n * DD + 2 * l + 1] = sy;
}

// ---------------------------------------------------------------------------
// Fused node MLP (MFMA): out = relu( relu([x|Hsum]@Wn + ub1 + deg*vv) @ U2 + ub2 )
__device__ inline int hs_idx(int m, int j) {
    return m * 128 + ((((j >> 2) ^ (m & 31)) << 2) | (j & 3));
}

__global__ __launch_bounds__(256, 2)
void node_mfma(const float* __restrict__ x, float* outHsum,
               const ushort_t* __restrict__ wnp, const ushort_t* __restrict__ u2p,
               const int* __restrict__ deg, const float* __restrict__ vv,
               const float* __restrict__ ub1, const float* __restrict__ ub2) {
    __shared__ __align__(16) float    Hs[128 * 128];
    __shared__ __align__(16) ushort_t Wst[4096];
    const int t = threadIdx.x, w = t >> 6, l = t & 63;
    const int lh = l >> 5, ln = l & 31;
    const int base = blockIdx.x * 128;
    const int row = base + w * 32 + ln;
    const int rowc = min(row, NNODES - 1);
    const float* ax = x + (size_t)rowc * DD;
    const float* ah = outHsum + (size_t)rowc * DD;

    f32x16 acc[4];
#pragma unroll
    for (int tt = 0; tt < 4; ++tt)
#pragma unroll
        for (int q = 0; q < 16; ++q) acc[tt][q] = 0.f;

    float4 pfh = *(const float4*)(wnp + t * 8);
    float4 pfl = *(const float4*)(wnp + 2048 + t * 8);
    for (int u = 0; u < 16; ++u) {
        __syncthreads();
        *(float4*)(Wst + t * 8)        = pfh;
        *(float4*)(Wst + 2048 + t * 8) = pfl;
        const int k = u * 16 + lh * 8;
        const float* src = (k < 128) ? (ax + k) : (ah + (k - 128));
        float4 a0 = *(const float4*)(src);
        float4 a1 = *(const float4*)(src + 4);
        if (u < 15) {
            pfh = *(const float4*)(wnp + (u + 1) * 4096 + t * 8);
            pfl = *(const float4*)(wnp + (u + 1) * 4096 + 2048 + t * 8);
        }
        float av[8] = {a0.x, a0.y, a0.z, a0.w, a1.x, a1.y, a1.z, a1.w};
        bf16x8 a_hi, a_lo;
#pragma unroll
        for (int q = 0; q < 8; ++q) {
            ushort_t h, lo16;
            bf16_split(av[q], h, lo16);
            a_hi[q] = (short)h; a_lo[q] = (short)lo16;
        }
        __syncthreads();
#pragma unroll
        for (int tt = 0; tt < 4; ++tt) {
            const int boff = (lh * 128 + tt * 32 + ln) * 8;
            bf16x8 bh = *(const bf16x8*)(Wst + boff);
            bf16x8 bl = *(const bf16x8*)(Wst + 2048 + boff);
            acc[tt] = __builtin_amdgcn_mfma_f32_32x32x16_bf16(a_hi, bh, acc[tt], 0, 0, 0);
            acc[tt] = __builtin_amdgcn_mfma_f32_32x32x16_bf16(a_hi, bl, acc[tt], 0, 0, 0);
            acc[tt] = __builtin_amdgcn_mfma_f32_32x32x16_bf16(a_lo, bh, acc[tt], 0, 0, 0);
        }
    }

    float4 pfh2 = *(const float4*)(u2p + t * 8);
    float4 pfl2 = *(const float4*)(u2p + 2048 + t * 8);

    float b1v[4], vvv[4];
#pragma unroll
    for (int tt = 0; tt < 4; ++tt) {
        b1v[tt] = ub1[tt * 32 + ln];
        vvv[tt] = vv[tt * 32 + ln];
    }
#pragma unroll
    for (int tt = 0; tt < 4; ++tt) {
#pragma unroll
        for (int r = 0; r < 16; ++r) {
            int mrow = w * 32 + (r & 3) + 8 * (r >> 2) + 4 * lh;
            int n = min(base + mrow, NNODES - 1);
            float dg = (float)deg[n];
            float g = acc[tt][r] + b1v[tt] + dg * vvv[tt];
            Hs[hs_idx(mrow, tt * 32 + ln)] = fmaxf(g, 0.f);
            acc[tt][r] = 0.f;
        }
    }

    for (int u = 0; u < 8; ++u) {
        __syncthreads();
        *(float4*)(Wst + t * 8)        = pfh2;
        *(float4*)(Wst + 2048 + t * 8) = pfl2;
        if (u < 7) {
            pfh2 = *(const float4*)(u2p + (u + 1) * 4096 + t * 8);
            pfl2 = *(const float4*)(u2p + (u + 1) * 4096 + 2048 + t * 8);
        }
        __syncthreads();
        const int m  = w * 32 + ln;
        const int s0 = u * 4 + lh * 2;
        float4 f0 = *(const float4*)(Hs + m * 128 + (((s0    ) ^ ln) << 2));
        float4 f1 = *(const float4*)(Hs + m * 128 + (((s0 + 1) ^ ln) << 2));
        float fv[8] = {f0.x, f0.y, f0.z, f0.w, f1.x, f1.y, f1.z, f1.w};
        bf16x8 a_hi, a_lo;
#pragma unroll
        for (int q = 0; q < 8; ++q) {
            ushort_t h, lo16;
            bf16_split(fv[q], h, lo16);
            a_hi[q] = (short)h; a_lo[q] = (short)lo16;
        }
#pragma unroll
        for (int tt = 0; tt < 4; ++tt) {
            const int boff = (lh * 128 + tt * 32 + ln) * 8;
            bf16x8 bh = *(const bf16x8*)(Wst + boff);
            bf16x8 bl = *(const bf16x8*)(Wst + 2048 + boff);
            acc[tt] = __builtin_amdgcn_mfma_f32_32x32x16_bf16(a_hi, bh, acc[tt], 0, 0, 0);
            acc[tt] = __builtin_amdgcn_mfma_f32_32x32x16_bf16(a_hi, bl, acc[tt], 0, 0, 0);
            acc[tt] = __builtin_amdgcn_mfma_f32_32x32x16_bf16(a_lo, bh, acc[tt], 0, 0, 0);
        }
    }

    float b2v[4];
#pragma unroll
    for (int tt = 0; tt < 4; ++tt) b2v[tt] = ub2[tt * 32 + ln];
#pragma unroll
    for (int tt = 0; tt < 4; ++tt) {
#pragma unroll
        for (int r = 0; r < 16; ++r) {
            int mrow = w * 32 + (r & 3) + 8 * (r >> 2) + 4 * lh;
            int n = base + mrow;
            if (n < NNODES)
                outHsum[(size_t)n * DD + tt * 32 + ln] =
                    fmaxf(acc[tt][r] + b2v[tt], 0.f);
        }
    }
}

// ---------------------------------------------------------------------------
// FALLBACK MFMA edge kernel (rounds 3-5, proven)
template <int MODE>
__global__ __launch_bounds__(256, 2)
void edge_mfma(const ushort_t* __restrict__ xh, const ushort_t* __restrict__ xl,
               const ushort_t* __restrict__ w1p, const ushort_t* __restrict__ w2p,
               const int* __restrict__ ei, const int* __restrict__ elist,
               const float* __restrict__ b1, const float* __restrict__ b2,
               float* agg) {
    __shared__ __align__(16) float    Hsl[128 * 128];
    __shared__ __align__(16) ushort_t Wst[4096];
    const int t  = threadIdx.x;
    const int w  = t >> 6;
    const int l  = t & 63;
    const int lh = l >> 5;
    const int ln = l & 31;
    int eg;
    if (MODE == 1) eg = elist[blockIdx.x * EB + w * 32 + ln];
    else           eg = blockIdx.x * EB + w * 32 + ln;
    const int rv = ei[eg];
    const int cv = ei[NEDGES + eg];
    float bias1[4], bias2[4];
#pragma unroll
    for (int tt = 0; tt < 4; ++tt) {
        bias1[tt] = b1[tt * 32 + ln];
        bias2[tt] = b2[tt * 32 + ln];
    }
    f32x16 acc[4];
#pragma unroll
    for (int tt = 0; tt < 4; ++tt)
#pragma unroll
        for (int q = 0; q < 16; ++q) acc[tt][q] = 0.f;
    bf16x8 a_hi_next = *(const bf16x8*)(xh + (size_t)rv * DD + lh * 8);
    bf16x8 a_lo_next = *(const bf16x8*)(xl + (size_t)rv * DD + lh * 8);
    float4 pfh = *(const float4*)(w1p + t * 8);
    float4 pfl = *(const float4*)(w1p + 2048 + t * 8);
    for (int u = 0; u < 16; ++u) {
        __syncthreads();
        *(float4*)(Wst + t * 8)        = pfh;
        *(float4*)(Wst + 2048 + t * 8) = pfl;
        bf16x8 a_hi = a_hi_next, a_lo = a_lo_next;
        if (u < 15) {
            pfh = *(const float4*)(w1p + (u + 1) * 4096 + t * 8);
            pfl = *(const float4*)(w1p + (u + 1) * 4096 + 2048 + t * 8);
            int kk = (u + 1) * 16 + lh * 8;
            const int node = (kk < 128) ? rv : cv;
            const int off  = kk & 127;
            a_hi_next = *(const bf16x8*)(xh + (size_t)node * DD + off);
            a_lo_next = *(const bf16x8*)(xl + (size_t)node * DD + off);
        }
        __syncthreads();
#pragma unroll
        for (int tt = 0; tt < 4; ++tt) {
            const int boff = (lh * 128 + tt * 32 + ln) * 8;
            bf16x8 bh = *(const bf16x8*)(Wst + boff);
            bf16x8 bl = *(const bf16x8*)(Wst + 2048 + boff);
            acc[tt] = __builtin_amdgcn_mfma_f32_32x32x16_bf16(a_hi, bh, acc[tt], 0, 0, 0);
            acc[tt] = __builtin_amdgcn_mfma_f32_32x32x16_bf16(a_hi, bl, acc[tt], 0, 0, 0);
            acc[tt] = __builtin_amdgcn_mfma_f32_32x32x16_bf16(a_lo, bh, acc[tt], 0, 0, 0);
        }
    }
    pfh = *(const float4*)(w2p + t * 8);
    pfl = *(const float4*)(w2p + 2048 + t * 8);
#pragma unroll
    for (int tt = 0; tt < 4; ++tt) {
#pragma unroll
        for (int r = 0; r < 16; ++r) {
            int mrow = w * 32 + (r & 3) + 8 * (r >> 2) + 4 * lh;
            int j    = tt * 32 + ln;
            Hsl[hs_idx(mrow, j)] = fmaxf(acc[tt][r] + bias1[tt], 0.f);
            acc[tt][r] = 0.f;
        }
    }
    for (int u = 0; u < 8; ++u) {
        __syncthreads();
        *(float4*)(Wst + t * 8)        = pfh;
        *(float4*)(Wst + 2048 + t * 8) = pfl;
        if (u < 7) {
            pfh = *(const float4*)(w2p + (u + 1) * 4096 + t * 8);
            pfl = *(const float4*)(w2p + (u + 1) * 4096 + 2048 + t * 8);
        }
        __syncthreads();
        const int m  = w * 32 + ln;
        const int s0 = u * 4 + lh * 2;
        float4 f0 = *(const float4*)(Hsl + m * 128 + (((s0    ) ^ ln) << 2));
        float4 f1 = *(const float4*)(Hsl + m * 128 + (((s0 + 1) ^ ln) << 2));
        float fv[8] = {f0.x, f0.y, f0.z, f0.w, f1.x, f1.y, f1.z, f1.w};
        bf16x8 a_hi, a_lo;
#pragma unroll
        for (int q = 0; q < 8; ++q) {
            ushort_t h, lo16;
            bf16_split(fv[q], h, lo16);
            a_hi[q] = (short)h;
            a_lo[q] = (short)lo16;
        }
#pragma unroll
        for (int tt = 0; tt < 4; ++tt) {
            const int boff = (lh * 128 + tt * 32 + ln) * 8;
            bf16x8 bh = *(const bf16x8*)(Wst + boff);
            bf16x8 bl = *(const bf16x8*)(Wst + 2048 + boff);
            acc[tt] = __builtin_amdgcn_mfma_f32_32x32x16_bf16(a_hi, bh, acc[tt], 0, 0, 0);
            acc[tt] = __builtin_amdgcn_mfma_f32_32x32x16_bf16(a_hi, bl, acc[tt], 0, 0, 0);
            acc[tt] = __builtin_amdgcn_mfma_f32_32x32x16_bf16(a_lo, bh, acc[tt], 0, 0, 0);
        }
    }
    if (MODE == 1) {
        float s[4] = {0.f, 0.f, 0.f, 0.f};
        int cur = __shfl(cv, 0, 64);
#pragma unroll
        for (int row = 0; row < 32; ++row) {
            const int r = (row & 3) | ((row >> 3) << 2);
            const int h = (row >> 2) & 1;
            int nd = __shfl(cv, row, 64);
            if (nd != cur) {
                if (lh == 0) {
#pragma unroll
                    for (int tt = 0; tt < 4; ++tt)
                        atomicAdd(agg + (size_t)cur * DD + tt * 32 + ln, s[tt]);
                }
#pragma unroll
                for (int tt = 0; tt < 4; ++tt) s[tt] = 0.f;
                cur = nd;
            }
#pragma unroll
            for (int tt = 0; tt < 4; ++tt) {
                float mine  = acc[tt][r];
                float other = __shfl_xor(mine, 32, 64);
                float v = (h == lh) ? mine : other;
                s[tt] += v + bias2[tt];
            }
        }
        if (lh == 0) {
#pragma unroll
            for (int tt = 0; tt < 4; ++tt)
                atomicAdd(agg + (size_t)cur * DD + tt * 32 + ln, s[tt]);
        }
    } else {
        int cn[16];
#pragma unroll
        for (int r = 0; r < 16; ++r) {
            int mr = (r & 3) + 8 * (r >> 2) + 4 * lh;
            cn[r] = __shfl(cv, mr, 64);
        }
#pragma unroll
        for (int tt = 0; tt < 4; ++tt) {
#pragma unroll
            for (int r = 0; r < 16; ++r) {
                atomicAdd(agg + (size_t)cn[r] * DD + tt * 32 + ln,
                          acc[tt][r] + bias2[tt]);
            }
        }
    }
}

#define TE 64
#define KT 16
#define AX_S 260
#define HS_S 132
#define AX_WORDS (TE * AX_S)
#define WT_WORDS (KT * DD)
#define SMEM_WORDS (AX_WORDS + WT_WORDS + TE)

__global__ __launch_bounds__(256, 2)
void node_kernel(const float* __restrict__ x,
                 float* aggout,
                 const float* __restrict__ U1, const float* __restrict__ c1,
                 const float* __restrict__ U2, const float* __restrict__ c2) {
    __shared__ float smem[SMEM_WORDS];
    float* Ax = smem;
    float* Hss = smem;
    float* Wt = smem + AX_WORDS;
    const int t = threadIdx.x;
    const int base = blockIdx.x * TE;
    {
        const int e = t & 63;
        const int q = t >> 6;
        const int n = base + e;
        const bool valid = n < NNODES;
        const float* s1 = x + (size_t)n * DD;
        const float* s2 = aggout + (size_t)n * DD;
#pragma unroll
        for (int ci = 0; ci < 16; ++ci) {
            const int k4 = ci * 4 + q;
            float4 v = make_float4(0.f, 0.f, 0.f, 0.f);
            if (valid) {
                if (k4 < 32) v = *(const float4*)(s1 + k4 * 4);
                else         v = *(const float4*)(s2 + (k4 - 32) * 4);
            }
            *(float4*)(Ax + e * AX_S + k4 * 4) = v;
        }
    }
    const int jg = t & 31;
    const int eg2 = t >> 5;
    const int j0 = jg * 4;
    const float4 b1v = *(const float4*)(c1 + j0);
    const float4 b2v = *(const float4*)(c2 + j0);
    float acc[8][4];
#pragma unroll
    for (int i = 0; i < 8; ++i)
        acc[i][0] = acc[i][1] = acc[i][2] = acc[i][3] = 0.f;
    for (int kb = 0; kb < 256 / KT; ++kb) {
        __syncthreads();
        {
            const float* src = U1 + kb * KT * DD;
#pragma unroll
            for (int u = 0; u < 2; ++u) {
                const int f4i = u * 256 + t;
                *(float4*)(Wt + f4i * 4) = *(const float4*)(src + f4i * 4);
            }
        }
        __syncthreads();
        float4 Bc[KT];
#pragma unroll
        for (int kk = 0; kk < KT; ++kk)
            Bc[kk] = *(const float4*)(Wt + kk * DD + j0);
#pragma unroll
        for (int i = 0; i < 8; ++i) {
            const float* arow = Ax + (i * 8 + eg2) * AX_S + kb * KT;
            float a[KT];
#pragma unroll
            for (int kc = 0; kc < KT / 4; ++kc) {
                const float4 av = *(const float4*)(arow + kc * 4);
                a[kc * 4 + 0] = av.x; a[kc * 4 + 1] = av.y;
                a[kc * 4 + 2] = av.z; a[kc * 4 + 3] = av.w;
            }
#pragma unroll
            for (int kk = 0; kk < KT; ++kk) {
                acc[i][0] = fmaf(a[kk], Bc[kk].x, acc[i][0]);
                acc[i][1] = fmaf(a[kk], Bc[kk].y, acc[i][1]);
                acc[i][2] = fmaf(a[kk], Bc[kk].z, acc[i][2]);
                acc[i][3] = fmaf(a[kk], Bc[kk].w, acc[i][3]);
            }
        }
    }
    __syncthreads();
#pragma unroll
    for (int i = 0; i < 8; ++i) {
        float4 h;
        h.x = fmaxf(acc[i][0] + b1v.x, 0.f);
        h.y = fmaxf(acc[i][1] + b1v.y, 0.f);
        h.z = fmaxf(acc[i][2] + b1v.z, 0.f);
        h.w = fmaxf(acc[i][3] + b1v.w, 0.f);
        *(float4*)(Hss + (i * 8 + eg2) * HS_S + j0) = h;
        acc[i][0] = acc[i][1] = acc[i][2] = acc[i][3] = 0.f;
    }
    for (int kb = 0; kb < DD / KT; ++kb) {
        __syncthreads();
        {
            const float* src = U2 + kb * KT * DD;
#pragma unroll
            for (int u = 0; u < 2; ++u) {
                const int f4i = u * 256 + t;
                *(float4*)(Wt + f4i * 4) = *(const float4*)(src + f4i * 4);
            }
        }
        __syncthreads();
        float4 Bc[KT];
#pragma unroll
        for (int kk = 0; kk < KT; ++kk)
            Bc[kk] = *(const float4*)(Wt + kk * DD + j0);
#pragma unroll
        for (int i = 0; i < 8; ++i) {
            const float* arow = Hss + (i * 8 + eg2) * HS_S + kb * KT;
            float a[KT];
#pragma unroll
            for (int kc = 0; kc < KT / 4; ++kc) {
                const float4 av = *(const float4*)(arow + kc * 4);
                a[kc * 4 + 0] = av.x; a[kc * 4 + 1] = av.y;
                a[kc * 4 + 2] = av.z; a[kc * 4 + 3] = av.w;
            }
#pragma unroll
            for (int kk = 0; kk < KT; ++kk) {
                acc[i][0] = fmaf(a[kk], Bc[kk].x, acc[i][0]);
                acc[i][1] = fmaf(a[kk], Bc[kk].y, acc[i][1]);
                acc[i][2] = fmaf(a[kk], Bc[kk].z, acc[i][2]);
                acc[i][3] = fmaf(a[kk], Bc[kk].w, acc[i][3]);
            }
        }
    }
#pragma unroll
    for (int i = 0; i < 8; ++i) {
        const int n = base + i * 8 + eg2;
        if (n < NNODES) {
            float4 o;
            o.x = fmaxf(acc[i][0] + b2v.x, 0.f);
            o.y = fmaxf(acc[i][1] + b2v.y, 0.f);
            o.z = fmaxf(acc[i][2] + b2v.z, 0.f);
            o.w = fmaxf(acc[i][3] + b2v.w, 0.f);
            *(float4*)(aggout + (size_t)n * DD + j0) = o;
        }
    }
}

// ---------------------------------------------------------------------------
extern "C" void kernel_launch(void* const* d_in, const int* in_sizes, int n_in,
                              void* d_out, int out_size, void* d_ws, size_t ws_size,
                              hipStream_t stream) {
    const float* x   = (const float*)d_in[0];
    const int*   ei  = (const int*)d_in[1];
    const float* mW1 = (const float*)d_in[2];
    const float* mb1 = (const float*)d_in[3];
    const float* mW2 = (const float*)d_in[4];
    const float* mb2 = (const float*)d_in[5];
    const float* uW1 = (const float*)d_in[6];
    const float* ub1 = (const float*)d_in[7];
    const float* uW2 = (const float*)d_in[8];
    const float* ub2 = (const float*)d_in[9];
    float* out = (float*)d_out;   // Hsum buffer + final output

    const int n4 = NNODES * DD / 4;

    if (ws_size >= (size_t)WS_NEW) {
        float*    PQ   = (float*)((char*)d_ws + PQ_OFF2);
        ushort_t* w1p  = (ushort_t*)((char*)d_ws + W1P_OFF2);
        ushort_t* u2p  = (ushort_t*)((char*)d_ws + U2P_OFF2);
        ushort_t* wnp  = (ushort_t*)((char*)d_ws + WNP_OFF2);
        float*    W2U  = (float*)((char*)d_ws + W2U_OFF2);
        float*    vv   = (float*)((char*)d_ws + VV_OFF2);
        int*      deg  = (int*)((char*)d_ws + DEG_OFF2);
        int*      curb = (int*)((char*)d_ws + CUR_OFF2);
        int*      bsum = (int*)((char*)d_ws + BSUM_OFF2);

        if (ws_size >= (size_t)WS_NEW2) {
            // ------- per-node path: 11 launches, no atomics in edge accum -------
            int2* ep = (int2*)((char*)d_ws + EL_OFF2);
            zero_i32<<<(50048 + 255) / 256, 256, 0, stream>>>(deg, 50048);
            hist_kernel<<<(NEDGES + 255) / 256, 256, 0, stream>>>(ei, deg);
            scanA<<<NB_SCAN, 1024, 0, stream>>>(deg, curb, bsum);
            scanC2<<<NB_SCAN, 1024, 0, stream>>>(deg, curb, bsum);
            fill2_kernel<<<(NEDGES + 255) / 256, 256, 0, stream>>>(ei, curb, ep);
            pack3<<<256, 256, 0, stream>>>(mW1, uW2, uW1, w1p, u2p, wnp);
            w2u_vv<<<65, 256, 0, stream>>>(mW2, mb2, uW1, W2U, vv);
            pack_w<<<(128 * 128 + 255) / 256, 256, 0, stream>>>(W2U, wnp + 32768, 128);
            pq_gemm<<<dim3(391, 2), 256, 0, stream>>>(x, w1p, mb1, PQ);
            // curb is now row-END (fill2 advanced it deg[n] times)
            edge_pn<<<(NNODES + 3) / 4, 256, 0, stream>>>(PQ, ep, curb, deg, out);
            node_mfma<<<391, 256, 0, stream>>>(x, out, wnp, u2p, deg, vv, ub1, ub2);
        } else {
            // ------- round-7 proven path -------
            int* elst = (int*)((char*)d_ws + EL_OFF2);
            zero_kernel<<<(n4 + 255) / 256, 256, 0, stream>>>((float4*)out, n4);
            zero_i32<<<(50048 + 255) / 256, 256, 0, stream>>>(deg, 50048);
            hist_kernel<<<(NEDGES + 255) / 256, 256, 0, stream>>>(ei, deg);
            scanA<<<NB_SCAN, 1024, 0, stream>>>(deg, curb, bsum);
            scanB<<<1, 64, 0, stream>>>(bsum, NB_SCAN);
            scanC<<<NB_SCAN, 1024, 0, stream>>>(deg, curb, bsum);
            fill_kernel<<<(NEDGES + 255) / 256, 256, 0, stream>>>(ei, curb, elst);
            pack_w<<<(256 * 128 + 255) / 256, 256, 0, stream>>>(mW1, w1p, 256);
            pack_w<<<(128 * 128 + 255) / 256, 256, 0, stream>>>(uW2, u2p, 128);
            w2u_kernel<<<64, 256, 0, stream>>>(mW2, uW1, W2U);
            vvec_kernel<<<1, 128, 0, stream>>>(mb2, uW1, vv);
            pack_w<<<(128 * 128 + 255) / 256, 256, 0, stream>>>(uW1, wnp, 128);
            pack_w<<<(128 * 128 + 255) / 256, 256, 0, stream>>>(W2U, wnp + 32768, 128);
            pq_gemm<<<dim3(391, 2), 256, 0, stream>>>(x, w1p, mb1, PQ);
            edge_ew<<<(NEDGES + 511) / 512, 256, 0, stream>>>(PQ, ei, elst, out);
            node_mfma<<<391, 256, 0, stream>>>(x, out, wnp, u2p, deg, vv, ub1, ub2);
        }
        return;
    }

    // ---------------- fallback paths (rounds 2-5, proven) ----------------
    zero_kernel<<<(n4 + 255) / 256, 256, 0, stream>>>((float4*)out, n4);
    if (ws_size >= (size_t)WS_MIN) {
        ushort_t* xh  = (ushort_t*)((char*)d_ws + XH_OFF);
        ushort_t* xl  = (ushort_t*)((char*)d_ws + XL_OFF);
        ushort_t* w1p = (ushort_t*)((char*)d_ws + W1P_OFF);
        ushort_t* w2p = (ushort_t*)((char*)d_ws + W2P_OFF);
        pack_x<<<(NNODES * DD + 255) / 256, 256, 0, stream>>>(x, xh, xl);
        pack_w<<<(256 * 128 + 255) / 256, 256, 0, stream>>>(mW1, w1p, 256);
        pack_w<<<(128 * 128 + 255) / 256, 256, 0, stream>>>(mW2, w2p, 128);
        if (ws_size >= (size_t)WS_CSR) {
            int* deg    = (int*)((char*)d_ws + DEG_OFF);
            int* elist  = (int*)((char*)d_ws + ELIST_OFF);
            int* cursor = (int*)((char*)d_ws + CUR_OFF);
            zero_i32<<<(50048 + 255) / 256, 256, 0, stream>>>(deg, 50048);
            hist_kernel<<<(NEDGES + 255) / 256, 256, 0, stream>>>(ei, deg);
            scan_kernel<<<1, 1024, 0, stream>>>(deg, cursor);
            fill_kernel<<<(NEDGES + 255) / 256, 256, 0, stream>>>(ei, cursor, elist);
            edge_mfma<1><<<NEDGES / EB, 256, 0, stream>>>(
                xh, xl, w1p, w2p, ei, elist, mb1, mb2, out);
        } else {
            edge_mfma<0><<<NEDGES / EB, 256, 0, stream>>>(
                xh, xl, w1p, w2p, ei, (const int*)nullptr, mb1, mb2, out);
        }
    }
    node_kernel<<<(NNODES + TE - 1) / TE, 256, 0, stream>>>(x, out, uW1, ub1,
                                                            uW2, ub2);
}

// Round 11
// 314.998 us; speedup vs baseline: 1.3614x; 1.0223x over previous
//
#include <hip/hip_runtime.h>
#include <stdint.h>

typedef unsigned short ushort_t;

#define NNODES 50000
#define NEDGES 800000
#define DD 128
#define EB 128

typedef short bf16x8 __attribute__((ext_vector_type(8)));
typedef float f32x16 __attribute__((ext_vector_type(16)));

// ---------------- fallback ws layout (bytes) — rounds 3-5, proven ----------
#define XH_OFF    0u
#define XL_OFF    12800000u
#define W1P_OFF   25600000u
#define W2P_OFF   25731072u
#define WS_MIN    25796608u
#define DEG_OFF   25796608u
#define ELIST_OFF 25996800u
#define CUR_OFF   29196800u
#define WS_CSR    29396992u

// ---------------- factored-path ws layout (bytes) ----------------
#define PQ_OFF2   0u
#define W1P_OFF2  51200000u
#define U2P_OFF2  51331072u
#define WNP_OFF2  51396608u
#define W2U_OFF2  51527680u
#define VV_OFF2   51593216u
#define DEG_OFF2  51593728u
#define CUR_OFF2  51793920u
#define BSUM_OFF2 51994112u
#define EL_OFF2   51994368u
#define WS_NEW    55194368u
#define WS_NEW2   58394368u

#define NB_SCAN 49

// ---------------------------------------------------------------------------
__global__ void zero_kernel(float4* __restrict__ p, int n4) {
    int i = blockIdx.x * blockDim.x + threadIdx.x;
    if (i < n4) p[i] = make_float4(0.f, 0.f, 0.f, 0.f);
}
__global__ void zero_i32(int* __restrict__ p, int n) {
    int i = blockIdx.x * blockDim.x + threadIdx.x;
    if (i < n) p[i] = 0;
}

__device__ inline void bf16_split(float f, ushort_t& hi, ushort_t& lo) {
    uint32_t b = __float_as_uint(f);
    uint32_t hb = b & 0xFFFF0000u;
    hi = (ushort_t)(b >> 16);
    float lof = f - __uint_as_float(hb);
    lo = (ushort_t)(__float_as_uint(lof) >> 16);
}

__global__ void pack_x(const float* __restrict__ x,
                       ushort_t* __restrict__ xh, ushort_t* __restrict__ xl) {
    int i = blockIdx.x * blockDim.x + threadIdx.x;
    if (i >= NNODES * DD) return;
    ushort_t h, l;
    bf16_split(x[i], h, l);
    xh[i] = h; xl[i] = l;
}

__global__ void pack_w(const float* __restrict__ W, ushort_t* __restrict__ wp,
                       int K) {
    int i = blockIdx.x * blockDim.x + threadIdx.x;
    if (i >= K * 128) return;
    int k = i >> 7, n = i & 127;
    int base = (k >> 4) * 4096 + ((((k >> 3) & 1) * 128 + n) << 3) + (k & 7);
    ushort_t h, l;
    bf16_split(W[i], h, l);
    wp[base] = h; wp[base + 2048] = l;
}

// prep0: fused pack3 (blocks 0..255) + zero deg (blocks 256..451)
__global__ void prep0(const float* __restrict__ mW1, const float* __restrict__ uW2,
                      const float* __restrict__ uW1,
                      ushort_t* __restrict__ w1p, ushort_t* __restrict__ u2p,
                      ushort_t* __restrict__ wnp, int* __restrict__ deg) {
    if (blockIdx.x < 256) {
        int i = blockIdx.x * 256 + threadIdx.x;   // 0..65535
        const float* W; ushort_t* wp; int li;
        if (i < 32768)      { W = mW1; wp = w1p; li = i; }
        else if (i < 49152) { W = uW2; wp = u2p; li = i - 32768; }
        else                { W = uW1; wp = wnp; li = i - 49152; }
        int k = li >> 7, n = li & 127;
        int base = (k >> 4) * 4096 + ((((k >> 3) & 1) * 128 + n) << 3) + (k & 7);
        ushort_t h, l;
        bf16_split(W[li], h, l);
        wp[base] = h; wp[base + 2048] = l;
    } else {
        int j = (blockIdx.x - 256) * 256 + threadIdx.x;
        if (j < 50048) deg[j] = 0;
    }
}

// ---------------- CSR build ----------------
__global__ void hist_kernel(const int* __restrict__ ei, int* __restrict__ deg) {
    int i = blockIdx.x * blockDim.x + threadIdx.x;
    if (i < NEDGES) atomicAdd(&deg[ei[NEDGES + i]], 1);
}

// single-block scan (fallback path only)
__global__ __launch_bounds__(1024)
void scan_kernel(const int* __restrict__ deg, int* __restrict__ cursor) {
    __shared__ int part[1024];
    const int t = threadIdx.x;
    const int CH = 49;
    int s = 0;
#pragma unroll 1
    for (int i = 0; i < CH; ++i) {
        int idx = t * CH + i;
        if (idx < NNODES) s += deg[idx];
    }
    part[t] = s;
    __syncthreads();
    for (int d = 1; d < 1024; d <<= 1) {
        int v = (t >= d) ? part[t - d] : 0;
        __syncthreads();
        part[t] += v;
        __syncthreads();
    }
    int run = (t == 0) ? 0 : part[t - 1];
#pragma unroll 1
    for (int i = 0; i < CH; ++i) {
        int idx = t * CH + i;
        if (idx < NNODES) {
            cursor[idx] = run;
            run += deg[idx];
        }
    }
}

__global__ __launch_bounds__(1024)
void scanA(const int* __restrict__ deg, int* __restrict__ cur,
           int* __restrict__ bsum) {
    __shared__ int sm[1024];
    const int t = threadIdx.x;
    const int idx = blockIdx.x * 1024 + t;
    int d = (idx < NNODES) ? deg[idx] : 0;
    sm[t] = d;
    __syncthreads();
    for (int off = 1; off < 1024; off <<= 1) {
        int v = 0;
        if (t >= off) v = sm[t - off];
        __syncthreads();
        sm[t] += v;
        __syncthreads();
    }
    if (idx < NNODES) cur[idx] = sm[t];
    if (t == 1023) bsum[blockIdx.x] = sm[1023];
}
__global__ void scanB(int* __restrict__ bsum, int nb) {
    if (threadIdx.x == 0) {
        int run = 0;
        for (int i = 0; i < nb; ++i) { int v = bsum[i]; bsum[i] = run; run += v; }
    }
}
__global__ __launch_bounds__(1024)
void scanC(const int* __restrict__ deg, int* __restrict__ cur,
           const int* __restrict__ bsum) {
    const int idx = blockIdx.x * 1024 + threadIdx.x;
    if (idx < NNODES) cur[idx] = cur[idx] - deg[idx] + bsum[blockIdx.x];
}
__global__ __launch_bounds__(1024)
void scanC2(const int* __restrict__ deg, int* __restrict__ cur,
            const int* __restrict__ bsum) {
    int pre = 0;
#pragma unroll 1
    for (int j = 0; j < blockIdx.x; ++j) pre += bsum[j];
    const int idx = blockIdx.x * 1024 + threadIdx.x;
    if (idx < NNODES) cur[idx] = cur[idx] - deg[idx] + pre;
}

__global__ void fill_kernel(const int* __restrict__ ei, int* __restrict__ cursor,
                            int* __restrict__ elist) {
    int i = blockIdx.x * blockDim.x + threadIdx.x;
    if (i < NEDGES) {
        int pos = atomicAdd(&cursor[ei[NEDGES + i]], 1);
        elist[pos] = i;
    }
}
// fill3: write only SRC (4B) in dest-sorted order — edge_pn2 never needs dst
__global__ void fill3_kernel(const int* __restrict__ ei, int* __restrict__ cursor,
                             int* __restrict__ srcs) {
    int i = blockIdx.x * blockDim.x + threadIdx.x;
    if (i < NEDGES) {
        int pos = atomicAdd(&cursor[ei[NEDGES + i]], 1);
        srcs[pos] = ei[i];
    }
}

// ---------------- small precomputes ----------------
__global__ void w2u_kernel(const float* __restrict__ W2,
                           const float* __restrict__ U1, float* __restrict__ W2U) {
    int id = blockIdx.x * 256 + threadIdx.x;
    if (id >= 128 * 128) return;
    int i = id >> 7, j = id & 127;
    float s = 0.f;
    for (int k = 0; k < 128; ++k) s += W2[i * 128 + k] * U1[(128 + k) * 128 + j];
    W2U[id] = s;
}
__global__ void vvec_kernel(const float* __restrict__ b2,
                            const float* __restrict__ U1, float* __restrict__ vv) {
    int j = threadIdx.x;
    if (j >= 128) return;
    float s = 0.f;
    for (int k = 0; k < 128; ++k) s += b2[k] * U1[(128 + k) * 128 + j];
    vv[j] = s;
}
// w2u_vv_pack: W2U computed AND written directly in packed bf16 hi/lo fragment
// order into wnp2 = wnp+32768 (kills the fp32 roundtrip + extra pack launch).
__global__ void w2u_vv_pack(const float* __restrict__ W2, const float* __restrict__ b2,
                            const float* __restrict__ U1,
                            ushort_t* __restrict__ wnp2, float* __restrict__ vv) {
    if (blockIdx.x < 64) {
        int id = blockIdx.x * 256 + threadIdx.x;
        int i = id >> 7, j = id & 127;          // W2U elem (k=i, n=j)
        float s = 0.f;
        for (int k = 0; k < 128; ++k)
            s += W2[i * 128 + k] * U1[(128 + k) * 128 + j];
        int base = (i >> 4) * 4096 + ((((i >> 3) & 1) * 128 + j) << 3) + (i & 7);
        ushort_t h, l;
        bf16_split(s, h, l);
        wnp2[base] = h; wnp2[base + 2048] = l;
    } else if (threadIdx.x < 128) {
        int j = threadIdx.x;
        float s = 0.f;
        for (int k = 0; k < 128; ++k)
            s += b2[k] * U1[(128 + k) * 128 + j];
        vv[j] = s;
    }
}

// ---------------------------------------------------------------------------
// PQ GEMM (unchanged — control for the block-size experiment)
__global__ __launch_bounds__(256)
void pq_gemm(const float* __restrict__ x, const ushort_t* __restrict__ w1p,
             const float* __restrict__ b1, float* __restrict__ PQ) {
    __shared__ __align__(16) ushort_t Wst[4096];
    const int t = threadIdx.x, w = t >> 6, l = t & 63;
    const int lh = l >> 5, ln = l & 31;
    const int base = blockIdx.x * 128;
    const int c = blockIdx.y;
    const int row = base + w * 32 + ln;
    const float* ax = x + (size_t)min(row, NNODES - 1) * DD;
    const ushort_t* wt = w1p + c * 8 * 4096;

    f32x16 acc[4];
#pragma unroll
    for (int tt = 0; tt < 4; ++tt)
#pragma unroll
        for (int q = 0; q < 16; ++q) acc[tt][q] = 0.f;

    float4 pfh = *(const float4*)(wt + t * 8);
    float4 pfl = *(const float4*)(wt + 2048 + t * 8);
    for (int u = 0; u < 8; ++u) {
        __syncthreads();
        *(float4*)(Wst + t * 8)        = pfh;
        *(float4*)(Wst + 2048 + t * 8) = pfl;
        float4 a0 = *(const float4*)(ax + u * 16 + lh * 8);
        float4 a1 = *(const float4*)(ax + u * 16 + lh * 8 + 4);
        if (u < 7) {
            pfh = *(const float4*)(wt + (u + 1) * 4096 + t * 8);
            pfl = *(const float4*)(wt + (u + 1) * 4096 + 2048 + t * 8);
        }
        float av[8] = {a0.x, a0.y, a0.z, a0.w, a1.x, a1.y, a1.z, a1.w};
        bf16x8 a_hi, a_lo;
#pragma unroll
        for (int q = 0; q < 8; ++q) {
            ushort_t h, lo16;
            bf16_split(av[q], h, lo16);
            a_hi[q] = (short)h; a_lo[q] = (short)lo16;
        }
        __syncthreads();
#pragma unroll
        for (int tt = 0; tt < 4; ++tt) {
            const int boff = (lh * 128 + tt * 32 + ln) * 8;
            bf16x8 bh = *(const bf16x8*)(Wst + boff);
            bf16x8 bl = *(const bf16x8*)(Wst + 2048 + boff);
            acc[tt] = __builtin_amdgcn_mfma_f32_32x32x16_bf16(a_hi, bh, acc[tt], 0, 0, 0);
            acc[tt] = __builtin_amdgcn_mfma_f32_32x32x16_bf16(a_hi, bl, acc[tt], 0, 0, 0);
            acc[tt] = __builtin_amdgcn_mfma_f32_32x32x16_bf16(a_lo, bh, acc[tt], 0, 0, 0);
        }
    }
    float bias[4];
#pragma unroll
    for (int tt = 0; tt < 4; ++tt)
        bias[tt] = (c == 0) ? b1[tt * 32 + ln] : 0.f;
#pragma unroll
    for (int tt = 0; tt < 4; ++tt) {
#pragma unroll
        for (int r = 0; r < 16; ++r) {
            int mrow = w * 32 + (r & 3) + 8 * (r >> 2) + 4 * lh;
            int n = base + mrow;
            if (n < NNODES)
                PQ[(size_t)n * 256 + c * 128 + tt * 32 + ln] = acc[tt][r] + bias[tt];
        }
    }
}

// ---------------------------------------------------------------------------
// Edge elementwise (round-7 proven fallback)
#define EW_C 4
__global__ __launch_bounds__(256)
void edge_ew(const float* __restrict__ PQ, const int* __restrict__ ei,
             const int* __restrict__ elist, float* Hsum) {
    const int t = threadIdx.x, w = t >> 6, l = t & 63;
    const int start = blockIdx.x * 512 + w * 128;
    if (start >= NEDGES) return;
    const int end = min(start + 128, NEDGES);

    float sx = 0.f, sy = 0.f;
    int cur = -1;
    int rv[EW_C] = {0, 0, 0, 0}, cv[EW_C] = {0, 0, 0, 0};
    float px[EW_C] = {0, 0, 0, 0}, py[EW_C] = {0, 0, 0, 0};
    float qx[EW_C] = {0, 0, 0, 0}, qy[EW_C] = {0, 0, 0, 0};

    const int navail = min(EW_C, end - start);
#pragma unroll
    for (int i = 0; i < EW_C; ++i)
        if (i < navail) {
            int e = elist[start + i];
            rv[i] = ei[e]; cv[i] = ei[NEDGES + e];
        }
#pragma unroll
    for (int i = 0; i < EW_C; ++i)
        if (i < navail) {
            float2 p = *(const float2*)(PQ + (size_t)rv[i] * 256 + 2 * l);
            float2 q = *(const float2*)(PQ + (size_t)cv[i] * 256 + 128 + 2 * l);
            px[i] = p.x; py[i] = p.y; qx[i] = q.x; qy[i] = q.y;
        }

    for (int pos = start; pos < end; pos += EW_C) {
        const int cnt = min(EW_C, end - pos);
        int nn = end - (pos + EW_C);
        nn = nn < 0 ? 0 : (nn > EW_C ? EW_C : nn);
        int nrv[EW_C] = {0, 0, 0, 0}, ncv[EW_C] = {0, 0, 0, 0};
        float npx[EW_C] = {0, 0, 0, 0}, npy[EW_C] = {0, 0, 0, 0};
        float nqx[EW_C] = {0, 0, 0, 0}, nqy[EW_C] = {0, 0, 0, 0};
#pragma unroll
        for (int i = 0; i < EW_C; ++i)
            if (i < nn) {
                int e = elist[pos + EW_C + i];
                nrv[i] = ei[e]; ncv[i] = ei[NEDGES + e];
            }
#pragma unroll
        for (int i = 0; i < EW_C; ++i)
            if (i < nn) {
                float2 p = *(const float2*)(PQ + (size_t)nrv[i] * 256 + 2 * l);
                float2 q = *(const float2*)(PQ + (size_t)ncv[i] * 256 + 128 + 2 * l);
                npx[i] = p.x; npy[i] = p.y; nqx[i] = q.x; nqy[i] = q.y;
            }
#pragma unroll
        for (int i = 0; i < EW_C; ++i)
            if (i < cnt) {
                if (cv[i] != cur) {
                    if (cur >= 0) {
                        atomicAdd(Hsum + (size_t)cur * DD + 2 * l,     sx);
                        atomicAdd(Hsum + (size_t)cur * DD + 2 * l + 1, sy);
                    }
                    sx = 0.f; sy = 0.f; cur = cv[i];
                }
                sx += fmaxf(px[i] + qx[i], 0.f);
                sy += fmaxf(py[i] + qy[i], 0.f);
            }
#pragma unroll
        for (int i = 0; i < EW_C; ++i) {
            rv[i] = nrv[i]; cv[i] = ncv[i];
            px[i] = npx[i]; py[i] = npy[i]; qx[i] = nqx[i]; qy[i] = nqy[i];
        }
    }
    if (cur >= 0) {
        atomicAdd(Hsum + (size_t)cur * DD + 2 * l,     sx);
        atomicAdd(Hsum + (size_t)cur * DD + 2 * l + 1, sy);
    }
}

// ---------------------------------------------------------------------------
// Edge per-node v2: srcs is int (4B) — dst is implicit (own n). One plain store.
__global__ __launch_bounds__(256)
void edge_pn2(const float* __restrict__ PQ, const int* __restrict__ srcs,
              const int* __restrict__ endp, const int* __restrict__ deg,
              float* __restrict__ Hsum) {
    const int n = blockIdx.x * 4 + (threadIdx.x >> 6);
    if (n >= NNODES) return;
    const int l = threadIdx.x & 63;
    const int end = endp[n];
    const int start = end - deg[n];

    const float2 q = *(const float2*)(PQ + (size_t)n * 256 + 128 + 2 * l);
    float sx = 0.f, sy = 0.f;

    int s0[4];
    float2 p0[4];
    const int c0 = min(4, end - start);
#pragma unroll
    for (int i = 0; i < 4; ++i) s0[i] = (i < c0) ? srcs[start + i] : 0;
#pragma unroll
    for (int i = 0; i < 4; ++i)
        if (i < c0) p0[i] = *(const float2*)(PQ + (size_t)s0[i] * 256 + 2 * l);

    for (int e = start; e < end; e += 4) {
        const int cnt = min(4, end - e);
        int nn = end - (e + 4);
        nn = nn < 0 ? 0 : (nn > 4 ? 4 : nn);
        int s1[4];
        float2 p1[4];
#pragma unroll
        for (int i = 0; i < 4; ++i) s1[i] = (i < nn) ? srcs[e + 4 + i] : 0;
#pragma unroll
        for (int i = 0; i < 4; ++i)
            if (i < nn) p1[i] = *(const float2*)(PQ + (size_t)s1[i] * 256 + 2 * l);
#pragma unroll
        for (int i = 0; i < 4; ++i)
            if (i < cnt) {
                sx += fmaxf(p0[i].x + q.x, 0.f);
                sy += fmaxf(p0[i].y + q.y, 0.f);
            }
#pragma unroll
        for (int i = 0; i < 4; ++i) { s0[i] = s1[i]; p0[i] = p1[i]; }
    }

    Hsum[(size_t)n * DD + 2 * l]     = sx;
    Hsum[(size_t)n * DD + 2 * l + 1] = sy;
}

// ---------------------------------------------------------------------------
__device__ inline int hs_idx(int m, int j) {
    return m * 128 + ((((j >> 2) ^ (m & 31)) << 2) | (j & 3));
}

// node_mfma2: 64 rows/block, 128 threads (2 waves). LDS 40KB -> 4 blocks/CU.
__global__ __launch_bounds__(128)
void node_mfma2(const float* __restrict__ x, float* outHsum,
                const ushort_t* __restrict__ wnp, const ushort_t* __restrict__ u2p,
                const int* __restrict__ deg, const float* __restrict__ vv,
                const float* __restrict__ ub1, const float* __restrict__ ub2) {
    __shared__ __align__(16) float    Hs[64 * 128];   // 32 KB
    __shared__ __align__(16) ushort_t Wst[4096];      // 8 KB
    const int t = threadIdx.x, w = t >> 6, l = t & 63;
    const int lh = l >> 5, ln = l & 31;
    const int base = blockIdx.x * 64;
    const int row = base + w * 32 + ln;
    const int rowc = min(row, NNODES - 1);
    const float* ax = x + (size_t)rowc * DD;
    const float* ah = outHsum + (size_t)rowc * DD;

    f32x16 acc[4];
#pragma unroll
    for (int tt = 0; tt < 4; ++tt)
#pragma unroll
        for (int q = 0; q < 16; ++q) acc[tt][q] = 0.f;

    // staging: 128 threads cover 256 float4-slots per plane (t and t+128)
    float4 pfh0 = *(const float4*)(wnp + t * 8);
    float4 pfh1 = *(const float4*)(wnp + (t + 128) * 8);
    float4 pfl0 = *(const float4*)(wnp + 2048 + t * 8);
    float4 pfl1 = *(const float4*)(wnp + 2048 + (t + 128) * 8);
    // ---- GEMM1: K=256 over [x | Hsum] ----
    for (int u = 0; u < 16; ++u) {
        __syncthreads();
        *(float4*)(Wst + t * 8)                = pfh0;
        *(float4*)(Wst + (t + 128) * 8)        = pfh1;
        *(float4*)(Wst + 2048 + t * 8)         = pfl0;
        *(float4*)(Wst + 2048 + (t + 128) * 8) = pfl1;
        const int k = u * 16 + lh * 8;
        const float* src = (k < 128) ? (ax + k) : (ah + (k - 128));
        float4 a0 = *(const float4*)(src);
        float4 a1 = *(const float4*)(src + 4);
        if (u < 15) {
            const ushort_t* nx = wnp + (u + 1) * 4096;
            pfh0 = *(const float4*)(nx + t * 8);
            pfh1 = *(const float4*)(nx + (t + 128) * 8);
            pfl0 = *(const float4*)(nx + 2048 + t * 8);
            pfl1 = *(const float4*)(nx + 2048 + (t + 128) * 8);
        }
        float av[8] = {a0.x, a0.y, a0.z, a0.w, a1.x, a1.y, a1.z, a1.w};
        bf16x8 a_hi, a_lo;
#pragma unroll
        for (int q = 0; q < 8; ++q) {
            ushort_t h, lo16;
            bf16_split(av[q], h, lo16);
            a_hi[q] = (short)h; a_lo[q] = (short)lo16;
        }
        __syncthreads();
#pragma unroll
        for (int tt = 0; tt < 4; ++tt) {
            const int boff = (lh * 128 + tt * 32 + ln) * 8;
            bf16x8 bh = *(const bf16x8*)(Wst + boff);
            bf16x8 bl = *(const bf16x8*)(Wst + 2048 + boff);
            acc[tt] = __builtin_amdgcn_mfma_f32_32x32x16_bf16(a_hi, bh, acc[tt], 0, 0, 0);
            acc[tt] = __builtin_amdgcn_mfma_f32_32x32x16_bf16(a_hi, bl, acc[tt], 0, 0, 0);
            acc[tt] = __builtin_amdgcn_mfma_f32_32x32x16_bf16(a_lo, bh, acc[tt], 0, 0, 0);
        }
    }

    float4 p2h0 = *(const float4*)(u2p + t * 8);
    float4 p2h1 = *(const float4*)(u2p + (t + 128) * 8);
    float4 p2l0 = *(const float4*)(u2p + 2048 + t * 8);
    float4 p2l1 = *(const float4*)(u2p + 2048 + (t + 128) * 8);

    float b1v[4], vvv[4];
#pragma unroll
    for (int tt = 0; tt < 4; ++tt) {
        b1v[tt] = ub1[tt * 32 + ln];
        vvv[tt] = vv[tt * 32 + ln];
    }
#pragma unroll
    for (int tt = 0; tt < 4; ++tt) {
#pragma unroll
        for (int r = 0; r < 16; ++r) {
            int mrow = w * 32 + (r & 3) + 8 * (r >> 2) + 4 * lh;   // 0..63
            int n = min(base + mrow, NNODES - 1);
            float dg = (float)deg[n];
            float g = acc[tt][r] + b1v[tt] + dg * vvv[tt];
            Hs[hs_idx(mrow, tt * 32 + ln)] = fmaxf(g, 0.f);
            acc[tt][r] = 0.f;
        }
    }

    // ---- GEMM2: K=128 vs U2 ----
    for (int u = 0; u < 8; ++u) {
        __syncthreads();
        *(float4*)(Wst + t * 8)                = p2h0;
        *(float4*)(Wst + (t + 128) * 8)        = p2h1;
        *(float4*)(Wst + 2048 + t * 8)         = p2l0;
        *(float4*)(Wst + 2048 + (t + 128) * 8) = p2l1;
        if (u < 7) {
            const ushort_t* nx = u2p + (u + 1) * 4096;
            p2h0 = *(const float4*)(nx + t * 8);
            p2h1 = *(const float4*)(nx + (t + 128) * 8);
            p2l0 = *(const float4*)(nx + 2048 + t * 8);
            p2l1 = *(const float4*)(nx + 2048 + (t + 128) * 8);
        }
        __syncthreads();
        const int m  = w * 32 + ln;                 // 0..63
        const int s0 = u * 4 + lh * 2;
        float4 f0 = *(const float4*)(Hs + m * 128 + (((s0    ) ^ ln) << 2));
        float4 f1 = *(const float4*)(Hs + m * 128 + (((s0 + 1) ^ ln) << 2));
        float fv[8] = {f0.x, f0.y, f0.z, f0.w, f1.x, f1.y, f1.z, f1.w};
        bf16x8 a_hi, a_lo;
#pragma unroll
        for (int q = 0; q < 8; ++q) {
            ushort_t h, lo16;
            bf16_split(fv[q], h, lo16);
            a_hi[q] = (short)h; a_lo[q] = (short)lo16;
        }
#pragma unroll
        for (int tt = 0; tt < 4; ++tt) {
            const int boff = (lh * 128 + tt * 32 + ln) * 8;
            bf16x8 bh = *(const bf16x8*)(Wst + boff);
            bf16x8 bl = *(const bf16x8*)(Wst + 2048 + boff);
            acc[tt] = __builtin_amdgcn_mfma_f32_32x32x16_bf16(a_hi, bh, acc[tt], 0, 0, 0);
            acc[tt] = __builtin_amdgcn_mfma_f32_32x32x16_bf16(a_hi, bl, acc[tt], 0, 0, 0);
            acc[tt] = __builtin_amdgcn_mfma_f32_32x32x16_bf16(a_lo, bh, acc[tt], 0, 0, 0);
        }
    }

    float b2v[4];
#pragma unroll
    for (int tt = 0; tt < 4; ++tt) b2v[tt] = ub2[tt * 32 + ln];
#pragma unroll
    for (int tt = 0; tt < 4; ++tt) {
#pragma unroll
        for (int r = 0; r < 16; ++r) {
            int mrow = w * 32 + (r & 3) + 8 * (r >> 2) + 4 * lh;
            int n = base + mrow;
            if (n < NNODES)
                outHsum[(size_t)n * DD + tt * 32 + ln] =
                    fmaxf(acc[tt][r] + b2v[tt], 0.f);
        }
    }
}

// node_mfma (round-7 proven, for middle fallback path)
__global__ __launch_bounds__(256, 2)
void node_mfma(const float* __restrict__ x, float* outHsum,
               const ushort_t* __restrict__ wnp, const ushort_t* __restrict__ u2p,
               const int* __restrict__ deg, const float* __restrict__ vv,
               const float* __restrict__ ub1, const float* __restrict__ ub2) {
    __shared__ __align__(16) float    Hs2[128 * 128];
    __shared__ __align__(16) ushort_t Wst[4096];
    const int t = threadIdx.x, w = t >> 6, l = t & 63;
    const int lh = l >> 5, ln = l & 31;
    const int base = blockIdx.x * 128;
    const int row = base + w * 32 + ln;
    const int rowc = min(row, NNODES - 1);
    const float* ax = x + (size_t)rowc * DD;
    const float* ah = outHsum + (size_t)rowc * DD;

    f32x16 acc[4];
#pragma unroll
    for (int tt = 0; tt < 4; ++tt)
#pragma unroll
        for (int q = 0; q < 16; ++q) acc[tt][q] = 0.f;

    float4 pfh = *(const float4*)(wnp + t * 8);
    float4 pfl = *(const float4*)(wnp + 2048 + t * 8);
    for (int u = 0; u < 16; ++u) {
        __syncthreads();
        *(float4*)(Wst + t * 8)        = pfh;
        *(float4*)(Wst + 2048 + t * 8) = pfl;
        const int k = u * 16 + lh * 8;
        const float* src = (k < 128) ? (ax + k) : (ah + (k - 128));
        float4 a0 = *(const float4*)(src);
        float4 a1 = *(const float4*)(src + 4);
        if (u < 15) {
            pfh = *(const float4*)(wnp + (u + 1) * 4096 + t * 8);
            pfl = *(const float4*)(wnp + (u + 1) * 4096 + 2048 + t * 8);
        }
        float av[8] = {a0.x, a0.y, a0.z, a0.w, a1.x, a1.y, a1.z, a1.w};
        bf16x8 a_hi, a_lo;
#pragma unroll
        for (int q = 0; q < 8; ++q) {
            ushort_t h, lo16;
            bf16_split(av[q], h, lo16);
            a_hi[q] = (short)h; a_lo[q] = (short)lo16;
        }
        __syncthreads();
#pragma unroll
        for (int tt = 0; tt < 4; ++tt) {
            const int boff = (lh * 128 + tt * 32 + ln) * 8;
            bf16x8 bh = *(const bf16x8*)(Wst + boff);
            bf16x8 bl = *(const bf16x8*)(Wst + 2048 + boff);
            acc[tt] = __builtin_amdgcn_mfma_f32_32x32x16_bf16(a_hi, bh, acc[tt], 0, 0, 0);
            acc[tt] = __builtin_amdgcn_mfma_f32_32x32x16_bf16(a_hi, bl, acc[tt], 0, 0, 0);
            acc[tt] = __builtin_amdgcn_mfma_f32_32x32x16_bf16(a_lo, bh, acc[tt], 0, 0, 0);
        }
    }

    float4 pfh2 = *(const float4*)(u2p + t * 8);
    float4 pfl2 = *(const float4*)(u2p + 2048 + t * 8);

    float b1v[4], vvv[4];
#pragma unroll
    for (int tt = 0; tt < 4; ++tt) {
        b1v[tt] = ub1[tt * 32 + ln];
        vvv[tt] = vv[tt * 32 + ln];
    }
#pragma unroll
    for (int tt = 0; tt < 4; ++tt) {
#pragma unroll
        for (int r = 0; r < 16; ++r) {
            int mrow = w * 32 + (r & 3) + 8 * (r >> 2) + 4 * lh;
            int n = min(base + mrow, NNODES - 1);
            float dg = (float)deg[n];
            float g = acc[tt][r] + b1v[tt] + dg * vvv[tt];
            Hs2[hs_idx(mrow, tt * 32 + ln)] = fmaxf(g, 0.f);
            acc[tt][r] = 0.f;
        }
    }

    for (int u = 0; u < 8; ++u) {
        __syncthreads();
        *(float4*)(Wst + t * 8)        = pfh2;
        *(float4*)(Wst + 2048 + t * 8) = pfl2;
        if (u < 7) {
            pfh2 = *(const float4*)(u2p + (u + 1) * 4096 + t * 8);
            pfl2 = *(const float4*)(u2p + (u + 1) * 4096 + 2048 + t * 8);
        }
        __syncthreads();
        const int m  = w * 32 + ln;
        const int s0 = u * 4 + lh * 2;
        float4 f0 = *(const float4*)(Hs2 + m * 128 + (((s0    ) ^ ln) << 2));
        float4 f1 = *(const float4*)(Hs2 + m * 128 + (((s0 + 1) ^ ln) << 2));
        float fv[8] = {f0.x, f0.y, f0.z, f0.w, f1.x, f1.y, f1.z, f1.w};
        bf16x8 a_hi, a_lo;
#pragma unroll
        for (int q = 0; q < 8; ++q) {
            ushort_t h, lo16;
            bf16_split(fv[q], h, lo16);
            a_hi[q] = (short)h; a_lo[q] = (short)lo16;
        }
#pragma unroll
        for (int tt = 0; tt < 4; ++tt) {
            const int boff = (lh * 128 + tt * 32 + ln) * 8;
            bf16x8 bh = *(const bf16x8*)(Wst + boff);
            bf16x8 bl = *(const bf16x8*)(Wst + 2048 + boff);
            acc[tt] = __builtin_amdgcn_mfma_f32_32x32x16_bf16(a_hi, bh, acc[tt], 0, 0, 0);
            acc[tt] = __builtin_amdgcn_mfma_f32_32x32x16_bf16(a_hi, bl, acc[tt], 0, 0, 0);
            acc[tt] = __builtin_amdgcn_mfma_f32_32x32x16_bf16(a_lo, bh, acc[tt], 0, 0, 0);
        }
    }

    float b2v[4];
#pragma unroll
    for (int tt = 0; tt < 4; ++tt) b2v[tt] = ub2[tt * 32 + ln];
#pragma unroll
    for (int tt = 0; tt < 4; ++tt) {
#pragma unroll
        for (int r = 0; r < 16; ++r) {
            int mrow = w * 32 + (r & 3) + 8 * (r >> 2) + 4 * lh;
            int n = base + mrow;
            if (n < NNODES)
                outHsum[(size_t)n * DD + tt * 32 + ln] =
                    fmaxf(acc[tt][r] + b2v[tt], 0.f);
        }
    }
}

// ---------------------------------------------------------------------------
// FALLBACK MFMA edge kernel (rounds 3-5, proven)
template <int MODE>
__global__ __launch_bounds__(256, 2)
void edge_mfma(const ushort_t* __restrict__ xh, const ushort_t* __restrict__ xl,
               const ushort_t* __restrict__ w1p, const ushort_t* __restrict__ w2p,
               const int* __restrict__ ei, const int* __restrict__ elist,
               const float* __restrict__ b1, const float* __restrict__ b2,
               float* agg) {
    __shared__ __align__(16) float    Hsl[128 * 128];
    __shared__ __align__(16) ushort_t Wst[4096];
    const int t  = threadIdx.x;
    const int w  = t >> 6;
    const int l  = t & 63;
    const int lh = l >> 5;
    const int ln = l & 31;
    int eg;
    if (MODE == 1) eg = elist[blockIdx.x * EB + w * 32 + ln];
    else           eg = blockIdx.x * EB + w * 32 + ln;
    const int rv = ei[eg];
    const int cv = ei[NEDGES + eg];
    float bias1[4], bias2[4];
#pragma unroll
    for (int tt = 0; tt < 4; ++tt) {
        bias1[tt] = b1[tt * 32 + ln];
        bias2[tt] = b2[tt * 32 + ln];
    }
    f32x16 acc[4];
#pragma unroll
    for (int tt = 0; tt < 4; ++tt)
#pragma unroll
        for (int q = 0; q < 16; ++q) acc[tt][q] = 0.f;
    bf16x8 a_hi_next = *(const bf16x8*)(xh + (size_t)rv * DD + lh * 8);
    bf16x8 a_lo_next = *(const bf16x8*)(xl + (size_t)rv * DD + lh * 8);
    float4 pfh = *(const float4*)(w1p + t * 8);
    float4 pfl = *(const float4*)(w1p + 2048 + t * 8);
    for (int u = 0; u < 16; ++u) {
        __syncthreads();
        *(float4*)(Wst + t * 8)        = pfh;
        *(float4*)(Wst + 2048 + t * 8) = pfl;
        bf16x8 a_hi = a_hi_next, a_lo = a_lo_next;
        if (u < 15) {
            pfh = *(const float4*)(w1p + (u + 1) * 4096 + t * 8);
            pfl = *(const float4*)(w1p + (u + 1) * 4096 + 2048 + t * 8);
            int kk = (u + 1) * 16 + lh * 8;
            const int node = (kk < 128) ? rv : cv;
            const int off  = kk & 127;
            a_hi_next = *(const bf16x8*)(xh + (size_t)node * DD + off);
            a_lo_next = *(const bf16x8*)(xl + (size_t)node * DD + off);
        }
        __syncthreads();
#pragma unroll
        for (int tt = 0; tt < 4; ++tt) {
            const int boff = (lh * 128 + tt * 32 + ln) * 8;
            bf16x8 bh = *(const bf16x8*)(Wst + boff);
            bf16x8 bl = *(const bf16x8*)(Wst + 2048 + boff);
            acc[tt] = __builtin_amdgcn_mfma_f32_32x32x16_bf16(a_hi, bh, acc[tt], 0, 0, 0);
            acc[tt] = __builtin_amdgcn_mfma_f32_32x32x16_bf16(a_hi, bl, acc[tt], 0, 0, 0);
            acc[tt] = __builtin_amdgcn_mfma_f32_32x32x16_bf16(a_lo, bh, acc[tt], 0, 0, 0);
        }
    }
    pfh = *(const float4*)(w2p + t * 8);
    pfl = *(const float4*)(w2p + 2048 + t * 8);
#pragma unroll
    for (int tt = 0; tt < 4; ++tt) {
#pragma unroll
        for (int r = 0; r < 16; ++r) {
            int mrow = w * 32 + (r & 3) + 8 * (r >> 2) + 4 * lh;
            int j    = tt * 32 + ln;
            Hsl[hs_idx(mrow, j)] = fmaxf(acc[tt][r] + bias1[tt], 0.f);
            acc[tt][r] = 0.f;
        }
    }
    for (int u = 0; u < 8; ++u) {
        __syncthreads();
        *(float4*)(Wst + t * 8)        = pfh;
        *(float4*)(Wst + 2048 + t * 8) = pfl;
        if (u < 7) {
            pfh = *(const float4*)(w2p + (u + 1) * 4096 + t * 8);
            pfl = *(const float4*)(w2p + (u + 1) * 4096 + 2048 + t * 8);
        }
        __syncthreads();
        const int m  = w * 32 + ln;
        const int s0 = u * 4 + lh * 2;
        float4 f0 = *(const float4*)(Hsl + m * 128 + (((s0    ) ^ ln) << 2));
        float4 f1 = *(const float4*)(Hsl + m * 128 + (((s0 + 1) ^ ln) << 2));
        float fv[8] = {f0.x, f0.y, f0.z, f0.w, f1.x, f1.y, f1.z, f1.w};
        bf16x8 a_hi, a_lo;
#pragma unroll
        for (int q = 0; q < 8; ++q) {
            ushort_t h, lo16;
            bf16_split(fv[q], h, lo16);
            a_hi[q] = (short)h;
            a_lo[q] = (short)lo16;
        }
#pragma unroll
        for (int tt = 0; tt < 4; ++tt) {
            const int boff = (lh * 128 + tt * 32 + ln) * 8;
            bf16x8 bh = *(const bf16x8*)(Wst + boff);
            bf16x8 bl = *(const bf16x8*)(Wst + 2048 + boff);
            acc[tt] = __builtin_amdgcn_mfma_f32_32x32x16_bf16(a_hi, bh, acc[tt], 0, 0, 0);
            acc[tt] = __builtin_amdgcn_mfma_f32_32x32x16_bf16(a_hi, bl, acc[tt], 0, 0, 0);
            acc[tt] = __builtin_amdgcn_mfma_f32_32x32x16_bf16(a_lo, bh, acc[tt], 0, 0, 0);
        }
    }
    if (MODE == 1) {
        float s[4] = {0.f, 0.f, 0.f, 0.f};
        int cur = __shfl(cv, 0, 64);
#pragma unroll
        for (int row = 0; row < 32; ++row) {
            const int r = (row & 3) | ((row >> 3) << 2);
            const int h = (row >> 2) & 1;
            int nd = __shfl(cv, row, 64);
            if (nd != cur) {
                if (lh == 0) {
#pragma unroll
                    for (int tt = 0; tt < 4; ++tt)
                        atomicAdd(agg + (size_t)cur * DD + tt * 32 + ln, s[tt]);
                }
#pragma unroll
                for (int tt = 0; tt < 4; ++tt) s[tt] = 0.f;
                cur = nd;
            }
#pragma unroll
            for (int tt = 0; tt < 4; ++tt) {
                float mine  = acc[tt][r];
                float other = __shfl_xor(mine, 32, 64);
                float v = (h == lh) ? mine : other;
                s[tt] += v + bias2[tt];
            }
        }
        if (lh == 0) {
#pragma unroll
            for (int tt = 0; tt < 4; ++tt)
                atomicAdd(agg + (size_t)cur * DD + tt * 32 + ln, s[tt]);
        }
    } else {
        int cn[16];
#pragma unroll
        for (int r = 0; r < 16; ++r) {
            int mr = (r & 3) + 8 * (r >> 2) + 4 * lh;
            cn[r] = __shfl(cv, mr, 64);
        }
#pragma unroll
        for (int tt = 0; tt < 4; ++tt) {
#pragma unroll
            for (int r = 0; r < 16; ++r) {
                atomicAdd(agg + (size_t)cn[r] * DD + tt * 32 + ln,
                          acc[tt][r] + bias2[tt]);
            }
        }
    }
}

#define TE 64
#define KT 16
#define AX_S 260
#define HS_S 132
#define AX_WORDS (TE * AX_S)
#define WT_WORDS (KT * DD)
#define SMEM_WORDS (AX_WORDS + WT_WORDS + TE)

__global__ __launch_bounds__(256, 2)
void node_kernel(const float* __restrict__ x,
                 float* aggout,
                 const float* __restrict__ U1, const float* __restrict__ c1,
                 const float* __restrict__ U2, const float* __restrict__ c2) {
    __shared__ float smem[SMEM_WORDS];
    float* Ax = smem;
    float* Hss = smem;
    float* Wt = smem + AX_WORDS;
    const int t = threadIdx.x;
    const int base = blockIdx.x * TE;
    {
        const int e = t & 63;
        const int q = t >> 6;
        const int n = base + e;
        const bool valid = n < NNODES;
        const float* s1 = x + (size_t)n * DD;
        const float* s2 = aggout + (size_t)n * DD;
#pragma unroll
        for (int ci = 0; ci < 16; ++ci) {
            const int k4 = ci * 4 + q;
            float4 v = make_float4(0.f, 0.f, 0.f, 0.f);
            if (valid) {
                if (k4 < 32) v = *(const float4*)(s1 + k4 * 4);
                else         v = *(const float4*)(s2 + (k4 - 32) * 4);
            }
            *(float4*)(Ax + e * AX_S + k4 * 4) = v;
        }
    }
    const int jg = t & 31;
    const int eg2 = t >> 5;
    const int j0 = jg * 4;
    const float4 b1v = *(const float4*)(c1 + j0);
    const float4 b2v = *(const float4*)(c2 + j0);
    float acc[8][4];
#pragma unroll
    for (int i = 0; i < 8; ++i)
        acc[i][0] = acc[i][1] = acc[i][2] = acc[i][3] = 0.f;
    for (int kb = 0; kb < 256 / KT; ++kb) {
        __syncthreads();
        {
            const float* src = U1 + kb * KT * DD;
#pragma unroll
            for (int u = 0; u < 2; ++u) {
                const int f4i = u * 256 + t;
                *(float4*)(Wt + f4i * 4) = *(const float4*)(src + f4i * 4);
            }
        }
        __syncthreads();
        float4 Bc[KT];
#pragma unroll
        for (int kk = 0; kk < KT; ++kk)
            Bc[kk] = *(const float4*)(Wt + kk * DD + j0);
#pragma unroll
        for (int i = 0; i < 8; ++i) {
            const float* arow = Ax + (i * 8 + eg2) * AX_S + kb * KT;
            float a[KT];
#pragma unroll
            for (int kc = 0; kc < KT / 4; ++kc) {
                const float4 av = *(const float4*)(arow + kc * 4);
                a[kc * 4 + 0] = av.x; a[kc * 4 + 1] = av.y;
                a[kc * 4 + 2] = av.z; a[kc * 4 + 3] = av.w;
            }
#pragma unroll
            for (int kk = 0; kk < KT; ++kk) {
                acc[i][0] = fmaf(a[kk], Bc[kk].x, acc[i][0]);
                acc[i][1] = fmaf(a[kk], Bc[kk].y, acc[i][1]);
                acc[i][2] = fmaf(a[kk], Bc[kk].z, acc[i][2]);
                acc[i][3] = fmaf(a[kk], Bc[kk].w, acc[i][3]);
            }
        }
    }
    __syncthreads();
#pragma unroll
    for (int i = 0; i < 8; ++i) {
        float4 h;
        h.x = fmaxf(acc[i][0] + b1v.x, 0.f);
        h.y = fmaxf(acc[i][1] + b1v.y, 0.f);
        h.z = fmaxf(acc[i][2] + b1v.z, 0.f);
        h.w = fmaxf(acc[i][3] + b1v.w, 0.f);
        *(float4*)(Hss + (i * 8 + eg2) * HS_S + j0) = h;
        acc[i][0] = acc[i][1] = acc[i][2] = acc[i][3] = 0.f;
    }
    for (int kb = 0; kb < DD / KT; ++kb) {
        __syncthreads();
        {
            const float* src = U2 + kb * KT * DD;
#pragma unroll
            for (int u = 0; u < 2; ++u) {
                const int f4i = u * 256 + t;
                *(float4*)(Wt + f4i * 4) = *(const float4*)(src + f4i * 4);
            }
        }
        __syncthreads();
        float4 Bc[KT];
#pragma unroll
        for (int kk = 0; kk < KT; ++kk)
            Bc[kk] = *(const float4*)(Wt + kk * DD + j0);
#pragma unroll
        for (int i = 0; i < 8; ++i) {
            const float* arow = Hss + (i * 8 + eg2) * HS_S + kb * KT;
            float a[KT];
#pragma unroll
            for (int kc = 0; kc < KT / 4; ++kc) {
                const float4 av = *(const float4*)(arow + kc * 4);
                a[kc * 4 + 0] = av.x; a[kc * 4 + 1] = av.y;
                a[kc * 4 + 2] = av.z; a[kc * 4 + 3] = av.w;
            }
#pragma unroll
            for (int kk = 0; kk < KT; ++kk) {
                acc[i][0] = fmaf(a[kk], Bc[kk].x, acc[i][0]);
                acc[i][1] = fmaf(a[kk], Bc[kk].y, acc[i][1]);
                acc[i][2] = fmaf(a[kk], Bc[kk].z, acc[i][2]);
                acc[i][3] = fmaf(a[kk], Bc[kk].w, acc[i][3]);
            }
        }
    }
#pragma unroll
    for (int i = 0; i < 8; ++i) {
        const int n = base + i * 8 + eg2;
        if (n < NNODES) {
            float4 o;
            o.x = fmaxf(acc[i][0] + b2v.x, 0.f);
            o.y = fmaxf(acc[i][1] + b2v.y, 0.f);
            o.z = fmaxf(acc[i][2] + b2v.z, 0.f);
            o.w = fmaxf(acc[i][3] + b2v.w, 0.f);
            *(float4*)(aggout + (size_t)n * DD + j0) = o;
        }
    }
}

// ---------------------------------------------------------------------------
extern "C" void kernel_launch(void* const* d_in, const int* in_sizes, int n_in,
                              void* d_out, int out_size, void* d_ws, size_t ws_size,
                              hipStream_t stream) {
    const float* x   = (const float*)d_in[0];
    const int*   ei  = (const int*)d_in[1];
    const float* mW1 = (const float*)d_in[2];
    const float* mb1 = (const float*)d_in[3];
    const float* mW2 = (const float*)d_in[4];
    const float* mb2 = (const float*)d_in[5];
    const float* uW1 = (const float*)d_in[6];
    const float* ub1 = (const float*)d_in[7];
    const float* uW2 = (const float*)d_in[8];
    const float* ub2 = (const float*)d_in[9];
    float* out = (float*)d_out;

    const int n4 = NNODES * DD / 4;

    if (ws_size >= (size_t)WS_NEW) {
        float*    PQ   = (float*)((char*)d_ws + PQ_OFF2);
        ushort_t* w1p  = (ushort_t*)((char*)d_ws + W1P_OFF2);
        ushort_t* u2p  = (ushort_t*)((char*)d_ws + U2P_OFF2);
        ushort_t* wnp  = (ushort_t*)((char*)d_ws + WNP_OFF2);
        float*    W2U  = (float*)((char*)d_ws + W2U_OFF2);
        float*    vv   = (float*)((char*)d_ws + VV_OFF2);
        int*      deg  = (int*)((char*)d_ws + DEG_OFF2);
        int*      curb = (int*)((char*)d_ws + CUR_OFF2);
        int*      bsum = (int*)((char*)d_ws + BSUM_OFF2);

        if (ws_size >= (size_t)WS_NEW2) {
            // ------- per-node path: 9 launches -------
            int* srcs = (int*)((char*)d_ws + EL_OFF2);
            prep0<<<452, 256, 0, stream>>>(mW1, uW2, uW1, w1p, u2p, wnp, deg);
            hist_kernel<<<(NEDGES + 255) / 256, 256, 0, stream>>>(ei, deg);
            scanA<<<NB_SCAN, 1024, 0, stream>>>(deg, curb, bsum);
            scanC2<<<NB_SCAN, 1024, 0, stream>>>(deg, curb, bsum);
            fill3_kernel<<<(NEDGES + 255) / 256, 256, 0, stream>>>(ei, curb, srcs);
            w2u_vv_pack<<<65, 256, 0, stream>>>(mW2, mb2, uW1, wnp + 32768, vv);
            pq_gemm<<<dim3(391, 2), 256, 0, stream>>>(x, w1p, mb1, PQ);
            edge_pn2<<<(NNODES + 3) / 4, 256, 0, stream>>>(PQ, srcs, curb, deg, out);
            node_mfma2<<<(NNODES + 63) / 64, 128, 0, stream>>>(
                x, out, wnp, u2p, deg, vv, ub1, ub2);
        } else {
            // ------- round-7 proven path -------
            int* elst = (int*)((char*)d_ws + EL_OFF2);
            zero_kernel<<<(n4 + 255) / 256, 256, 0, stream>>>((float4*)out, n4);
            zero_i32<<<(50048 + 255) / 256, 256, 0, stream>>>(deg, 50048);
            hist_kernel<<<(NEDGES + 255) / 256, 256, 0, stream>>>(ei, deg);
            scanA<<<NB_SCAN, 1024, 0, stream>>>(deg, curb, bsum);
            scanB<<<1, 64, 0, stream>>>(bsum, NB_SCAN);
            scanC<<<NB_SCAN, 1024, 0, stream>>>(deg, curb, bsum);
            fill_kernel<<<(NEDGES + 255) / 256, 256, 0, stream>>>(ei, curb, elst);
            pack_w<<<(256 * 128 + 255) / 256, 256, 0, stream>>>(mW1, w1p, 256);
            pack_w<<<(128 * 128 + 255) / 256, 256, 0, stream>>>(uW2, u2p, 128);
            w2u_kernel<<<64, 256, 0, stream>>>(mW2, uW1, W2U);
            vvec_kernel<<<1, 128, 0, stream>>>(mb2, uW1, vv);
            pack_w<<<(128 * 128 + 255) / 256, 256, 0, stream>>>(uW1, wnp, 128);
            pack_w<<<(128 * 128 + 255) / 256, 256, 0, stream>>>(W2U, wnp + 32768, 128);
            pq_gemm<<<dim3(391, 2), 256, 0, stream>>>(x, w1p, mb1, PQ);
            edge_ew<<<(NEDGES + 511) / 512, 256, 0, stream>>>(PQ, ei, elst, out);
            node_mfma<<<391, 256, 0, stream>>>(x, out, wnp, u2p, deg, vv, ub1, ub2);
        }
        return;
    }

    // ---------------- fallback paths (rounds 2-5, proven) ----------------
    zero_kernel<<<(n4 + 255) / 256, 256, 0, stream>>>((float4*)out, n4);
    if (ws_size >= (size_t)WS_MIN) {
        ushort_t* xh  = (ushort_t*)((char*)d_ws + XH_OFF);
        ushort_t* xl  = (ushort_t*)((char*)d_ws + XL_OFF);
        ushort_t* w1p = (ushort_t*)((char*)d_ws + W1P_OFF);
        ushort_t* w2p = (ushort_t*)((char*)d_ws + W2P_OFF);
        pack_x<<<(NNODES * DD + 255) / 256, 256, 0, stream>>>(x, xh, xl);
        pack_w<<<(256 * 128 + 255) / 256, 256, 0, stream>>>(mW1, w1p, 256);
        pack_w<<<(128 * 128 + 255) / 256, 256, 0, stream>>>(mW2, w2p, 128);
        if (ws_size >= (size_t)WS_CSR) {
            int* deg    = (int*)((char*)d_ws + DEG_OFF);
            int* elist  = (int*)((char*)d_ws + ELIST_OFF);
            int* cursor = (int*)((char*)d_ws + CUR_OFF);
            zero_i32<<<(50048 + 255) / 256, 256, 0, stream>>>(deg, 50048);
            hist_kernel<<<(NEDGES + 255) / 256, 256, 0, stream>>>(ei, deg);
            scan_kernel<<<1, 1024, 0, stream>>>(deg, cursor);
            fill_kernel<<<(NEDGES + 255) / 256, 256, 0, stream>>>(ei, cursor, elist);
            edge_mfma<1><<<NEDGES / EB, 256, 0, stream>>>(
                xh, xl, w1p, w2p, ei, elist, mb1, mb2, out);
        } else {
            edge_mfma<0><<<NEDGES / EB, 256, 0, stream>>>(
                xh, xl, w1p, w2p, ei, (const int*)nullptr, mb1, mb2, out);
        }
    }
    node_kernel<<<(NNODES + TE - 1) / TE, 256, 0, stream>>>(x, out, uW1, ub1,
                                                            uW2, ub2);
}